// Round 3
// baseline (1961.961 us; speedup 1.0000x reference)
//
#include <hip/hip_runtime.h>

#define NTOK 2048      // BATCH*SEQ
#define SEQL 1024
#define DMODEL 1024
#define DINNER 2048
#define DSTATE 16
#define DTRANK 64
#define GCH 32         // scan chunks
#define LC 32          // steps per chunk

typedef __attribute__((ext_vector_type(8))) short short8;
typedef __attribute__((ext_vector_type(4))) float float4v;

__device__ __forceinline__ unsigned short f2bf(float f) {
    unsigned u = __float_as_uint(f);
    unsigned r = u + 0x7FFFu + ((u >> 16) & 1u);
    return (unsigned short)(r >> 16);
}
__device__ __forceinline__ float bf2f(unsigned short h) {
    return __uint_as_float(((unsigned)h) << 16);
}

// ---------------- LayerNorm: f32 in; bf16 out (inter-layer) or f32 out (final) ----------------
__global__ __launch_bounds__(256) void ln_kernel(
    const float* __restrict__ x, const float* __restrict__ g,
    const float* __restrict__ b, unsigned short* __restrict__ out_bf,
    float* __restrict__ out_f32) {
    int row = blockIdx.x;
    const float* xr = x + (size_t)row * DMODEL;
    int t = threadIdx.x;
    float4 v = ((const float4*)xr)[t];
    float s  = v.x + v.y + v.z + v.w;
    float ss = v.x*v.x + v.y*v.y + v.z*v.z + v.w*v.w;
    for (int o = 32; o; o >>= 1) { s += __shfl_xor(s, o); ss += __shfl_xor(ss, o); }
    __shared__ float red[8];
    int wv = t >> 6;
    if ((t & 63) == 0) { red[wv * 2] = s; red[wv * 2 + 1] = ss; }
    __syncthreads();
    s  = red[0] + red[2] + red[4] + red[6];
    ss = red[1] + red[3] + red[5] + red[7];
    float mu = s * (1.f / DMODEL);
    float rstd = rsqrtf(ss * (1.f / DMODEL) - mu * mu + 1e-5f);
    float4 gv = ((const float4*)g)[t];
    float4 bv = ((const float4*)b)[t];
    float o0 = (v.x - mu) * rstd * gv.x + bv.x;
    float o1 = (v.y - mu) * rstd * gv.y + bv.y;
    float o2 = (v.z - mu) * rstd * gv.z + bv.z;
    float o3 = (v.w - mu) * rstd * gv.w + bv.w;
    if (out_f32) {
        ((float4*)out_f32)[row * 256 + t] = make_float4(o0, o1, o2, o3);
    } else {
        ((ushort4*)out_bf)[row * 256 + t] =
            make_ushort4(f2bf(o0), f2bf(o1), f2bf(o2), f2bf(o3));
    }
}

// ---------------- GEMM: C[M,N] (f32) = A[M,K] (bf16) * B[N,K]^T (f32->bf16) ----------------
// 128x128 tile per 256-thread block, 4 waves in 2x2, 16x16x32 MFMA.
#define BK 32
#define LDSS 40   // LDS row stride in elements (80B): keeps 16B alignment
__global__ __launch_bounds__(256) void gemm_bt(
    const unsigned short* __restrict__ A, const float* __restrict__ B,
    float* __restrict__ C, int M, int N, int K, int accum) {
    __shared__ __attribute__((aligned(16))) unsigned short As[128 * LDSS];
    __shared__ __attribute__((aligned(16))) unsigned short Bs[128 * LDSS];
    int m0 = blockIdx.y * 128, n0 = blockIdx.x * 128;
    int t = threadIdx.x;
    int lane = t & 63, w = t >> 6;
    int wr = (w >> 1) * 64, wc = (w & 1) * 64;
    int tr = lane & 15, quad = lane >> 4;
    float4v acc[4][4];
    for (int mi = 0; mi < 4; ++mi)
        for (int ni = 0; ni < 4; ++ni)
            acc[mi][ni] = (float4v){0.f, 0.f, 0.f, 0.f};
    for (int k0 = 0; k0 < K; k0 += BK) {
        for (int rep = 0; rep < 4; ++rep) {
            int cidx = t + rep * 256;          // 0..1023
            int isB = cidx >> 9;
            int idx = cidx & 511;
            int row = idx >> 2, q = idx & 3;   // row 0..127, q 0..3 (8 elems each)
            uint4 v = make_uint4(0, 0, 0, 0);
            if (!isB) {
                v = *(const uint4*)(A + (size_t)(m0 + row) * K + k0 + q * 8);
            } else if (n0 + row < N) {
                const float* src = B + (size_t)(n0 + row) * K + k0 + q * 8;
                float4 f0 = ((const float4*)src)[0];
                float4 f1 = ((const float4*)src)[1];
                v.x = (unsigned)f2bf(f0.x) | ((unsigned)f2bf(f0.y) << 16);
                v.y = (unsigned)f2bf(f0.z) | ((unsigned)f2bf(f0.w) << 16);
                v.z = (unsigned)f2bf(f1.x) | ((unsigned)f2bf(f1.y) << 16);
                v.w = (unsigned)f2bf(f1.z) | ((unsigned)f2bf(f1.w) << 16);
            }
            unsigned short* dst = (isB ? Bs : As) + row * LDSS + q * 8;
            *(uint4*)dst = v;
        }
        __syncthreads();
        short8 af[4], bfr[4];
        for (int i = 0; i < 4; ++i)
            af[i] = *(const short8*)(As + (wr + i * 16 + tr) * LDSS + quad * 8);
        for (int i = 0; i < 4; ++i)
            bfr[i] = *(const short8*)(Bs + (wc + i * 16 + tr) * LDSS + quad * 8);
        for (int mi = 0; mi < 4; ++mi)
            for (int ni = 0; ni < 4; ++ni)
                acc[mi][ni] = __builtin_amdgcn_mfma_f32_16x16x32_bf16(
                    af[mi], bfr[ni], acc[mi][ni], 0, 0, 0);
        __syncthreads();
    }
    // C/D layout (m89-verified): col = lane&15, row = (lane>>4)*4 + reg
    for (int mi = 0; mi < 4; ++mi)
        for (int ni = 0; ni < 4; ++ni) {
            int col = n0 + wc + ni * 16 + tr;
            if (col < N) {
                int rowb = m0 + wr + mi * 16 + quad * 4;
                for (int r = 0; r < 4; ++r) {
                    float* pc = C + (size_t)(rowb + r) * N + col;
                    if (accum) *pc += acc[mi][ni][r]; else *pc = acc[mi][ni][r];
                }
            }
        }
}

// ---------------- causal depthwise conv(4) + bias + silu -> bf16 ----------------
__global__ __launch_bounds__(256) void conv_silu(
    const float* __restrict__ xz, const float* __restrict__ cw,
    const float* __restrict__ cb, unsigned short* __restrict__ xm_bf) {
    int idx = blockIdx.x * 256 + threadIdx.x;   // NTOK*DINNER
    int c = idx & (DINNER - 1);
    int tk = idx >> 11;
    int l = tk & (SEQL - 1);
    float4 wv = ((const float4*)cw)[c];
    float acc = cb[c];
    const float* base = xz + (size_t)tk * (2 * DINNER) + c;
    if (l >= 3) acc += base[-3 * 2 * DINNER] * wv.x;
    if (l >= 2) acc += base[-2 * 2 * DINNER] * wv.y;
    if (l >= 1) acc += base[-1 * 2 * DINNER] * wv.z;
    acc += base[0] * wv.w;
    float sv = acc / (1.f + expf(-acc));
    xm_bf[idx] = f2bf(sv);
}

// ---------------- extract dt-rank cols of xdbl as bf16 ----------------
__global__ __launch_bounds__(256) void extract_dt(
    const float* __restrict__ xdbl, unsigned short* __restrict__ out) {
    int i = blockIdx.x * 256 + threadIdx.x;   // NTOK*DTRANK
    int tk = i >> 6, r = i & 63;
    out[i] = f2bf(xdbl[(size_t)tk * 96 + r]);
}

// ---------------- scan phase A: local chunk recurrence -> h_end, sum(dt) ----------------
// dtm updated IN PLACE with softplus(dtm + bias).
__global__ __launch_bounds__(256) void scan_a(
    float* __restrict__ dtm, const float* __restrict__ dtb,
    const unsigned short* __restrict__ xm_bf, const float* __restrict__ xdbl,
    const float* __restrict__ A_log,
    float* __restrict__ h_end, float* __restrict__ S_chunk) {
    int bid = blockIdx.x;                 // GCH*2*8 = 512
    int g = bid >> 4, b = (bid >> 3) & 1, cbk = bid & 7;
    int c = cbk * 256 + threadIdx.x;
    __shared__ float Bsh[LC][16];
    for (int r = 0; r < 2; ++r) {
        int e = threadIdx.x + r * 256;
        int li = e >> 4, s = e & 15;
        Bsh[li][s] = xdbl[((size_t)(b * SEQL + g * LC + li)) * 96 + 64 + s];
    }
    __syncthreads();
    float a_l2[16], h[16];
#pragma unroll
    for (int s = 0; s < 16; ++s) {
        a_l2[s] = -expf(A_log[c * 16 + s]) * 1.44269504f;
        h[s] = 0.f;
    }
    float dtbias = dtb[c];
    float S = 0.f;
    int rowbase = b * SEQL + g * LC;
    for (int i = 0; i < LC; ++i) {
        size_t off = (size_t)(rowbase + i) * DINNER + c;
        float xv = dtm[off] + dtbias;
        float dtv = (xv > 15.f) ? xv : log1pf(expf(xv));
        dtm[off] = dtv;
        S += dtv;
        float u = bf2f(xm_bf[off]);
        float bu = dtv * u;
#pragma unroll
        for (int s = 0; s < 16; ++s) {
            float dA = exp2f(dtv * a_l2[s]);
            h[s] = dA * h[s] + Bsh[i][s] * bu;
        }
    }
    int gb = g * 2 + b;
#pragma unroll
    for (int s = 0; s < 16; ++s)
        h_end[((size_t)gb * 16 + s) * DINNER + c] = h[s];
    S_chunk[(size_t)gb * DINNER + c] = S;
}

// ---------------- scan phase B: combine chunks -> h_in per chunk ----------------
__global__ __launch_bounds__(256) void scan_b(
    const float* __restrict__ A_log, const float* __restrict__ S_chunk,
    const float* __restrict__ h_end, float* __restrict__ h_in) {
    int idx = blockIdx.x * 256 + threadIdx.x;   // 2*16*2048 = 65536
    int c = idx & (DINNER - 1);
    int s = (idx >> 11) & 15;
    int b = idx >> 15;
    float a_l2 = -expf(A_log[c * 16 + s]) * 1.44269504f;
    float h = 0.f;
    for (int g = 0; g < GCH; ++g) {
        int gb = g * 2 + b;
        h_in[((size_t)gb * 16 + s) * DINNER + c] = h;
        float P = exp2f(a_l2 * S_chunk[(size_t)gb * DINNER + c]);
        h = P * h + h_end[((size_t)gb * 16 + s) * DINNER + c];
    }
}

// ---------------- scan phase C: seeded recurrence -> y (D-skip + silu(z) fused) ----------------
__global__ __launch_bounds__(256) void scan_c(
    const float* __restrict__ dt_buf, const unsigned short* __restrict__ xm_bf,
    const float* __restrict__ xdbl, const float* __restrict__ A_log,
    const float* __restrict__ D_skip, const float* __restrict__ xz,
    const float* __restrict__ h_in, unsigned short* __restrict__ y_bf) {
    int bid = blockIdx.x;
    int g = bid >> 4, b = (bid >> 3) & 1, cbk = bid & 7;
    int c = cbk * 256 + threadIdx.x;
    __shared__ float BCsh[LC][32];
    for (int r = 0; r < 4; ++r) {
        int e = threadIdx.x + r * 256;
        int li = e >> 5, s = e & 31;
        BCsh[li][s] = xdbl[((size_t)(b * SEQL + g * LC + li)) * 96 + 64 + s];
    }
    __syncthreads();
    int gb = g * 2 + b;
    float a_l2[16], h[16];
#pragma unroll
    for (int s = 0; s < 16; ++s) {
        a_l2[s] = -expf(A_log[c * 16 + s]) * 1.44269504f;
        h[s] = h_in[((size_t)gb * 16 + s) * DINNER + c];
    }
    float dsk = D_skip[c];
    int rowbase = b * SEQL + g * LC;
    for (int i = 0; i < LC; ++i) {
        size_t off = (size_t)(rowbase + i) * DINNER + c;
        float dtv = dt_buf[off];
        float u = bf2f(xm_bf[off]);
        float bu = dtv * u;
        float y = 0.f;
#pragma unroll
        for (int s = 0; s < 16; ++s) {
            float dA = exp2f(dtv * a_l2[s]);
            h[s] = dA * h[s] + BCsh[i][s] * bu;
            y += h[s] * BCsh[i][16 + s];
        }
        y += u * dsk;
        float zv = xz[(size_t)(rowbase + i) * (2 * DINNER) + DINNER + c];
        y *= zv / (1.f + expf(-zv));
        y_bf[off] = f2bf(y);
    }
}

extern "C" void kernel_launch(void* const* d_in, const int* in_sizes, int n_in,
                              void* d_out, int out_size, void* d_ws, size_t ws_size,
                              hipStream_t stream) {
    const float* x_in   = (const float*)d_in[0];
    const float* in_w   = (const float*)d_in[1];
    const float* conv_w = (const float*)d_in[2];
    const float* conv_b = (const float*)d_in[3];
    const float* xp_w   = (const float*)d_in[4];
    const float* dt_w   = (const float*)d_in[5];
    const float* dt_b   = (const float*)d_in[6];
    const float* A_logp = (const float*)d_in[7];
    const float* Dsk    = (const float*)d_in[8];
    const float* out_w  = (const float*)d_in[9];
    const float* ln_g   = (const float*)d_in[10];
    const float* ln_b   = (const float*)d_in[11];
    float* outp = (float*)d_out;           // reference output dtype: float32

    char* p = (char*)d_ws;
    auto alloc = [&](size_t bytes) {
        void* r = (void*)p;
        p += (bytes + 255) & ~(size_t)255;
        return r;
    };
    float* x_res  = (float*)alloc((size_t)NTOK * DMODEL * 4);
    unsigned short* xn_bf = (unsigned short*)alloc((size_t)NTOK * DMODEL * 2);
    float* xz     = (float*)alloc((size_t)NTOK * 2 * DINNER * 4);
    unsigned short* xm_bf = (unsigned short*)alloc((size_t)NTOK * DINNER * 2);
    float* xdbl   = (float*)alloc((size_t)NTOK * 96 * 4);
    unsigned short* dtA_bf = (unsigned short*)alloc((size_t)NTOK * DTRANK * 2);
    float* dtm    = (float*)alloc((size_t)NTOK * DINNER * 4);   // holds dt after scan_a
    unsigned short* y_bf = (unsigned short*)alloc((size_t)NTOK * DINNER * 2);
    float* h_end  = (float*)alloc((size_t)GCH * 2 * 16 * DINNER * 4);
    float* h_in   = (float*)alloc((size_t)GCH * 2 * 16 * DINNER * 4);
    float* S_chunk = (float*)alloc((size_t)GCH * 2 * DINNER * 4);

    // residual stream init: x_res = x (f32 copy, d2d)
    hipMemcpyAsync(x_res, x_in, (size_t)NTOK * DMODEL * 4,
                   hipMemcpyDeviceToDevice, stream);

    for (int L = 0; L < 4; ++L) {
        const float* w_in  = in_w  + (size_t)L * 2 * DINNER * DMODEL;
        const float* w_cv  = conv_w + (size_t)L * DINNER * 4;
        const float* b_cv  = conv_b + (size_t)L * DINNER;
        const float* w_xp  = xp_w  + (size_t)L * 96 * DINNER;
        const float* w_dt  = dt_w  + (size_t)L * DINNER * DTRANK;
        const float* b_dt  = dt_b  + (size_t)L * DINNER;
        const float* al    = A_logp + (size_t)L * DINNER * DSTATE;
        const float* dskl  = Dsk   + (size_t)L * DINNER;
        const float* w_out = out_w + (size_t)L * DMODEL * DINNER;

        ln_kernel<<<NTOK, 256, 0, stream>>>(x_res, ln_g, ln_b, xn_bf, nullptr);
        gemm_bt<<<dim3(32, 16), 256, 0, stream>>>(xn_bf, w_in, xz,
                                                   NTOK, 2 * DINNER, DMODEL, 0);
        conv_silu<<<NTOK * DINNER / 256, 256, 0, stream>>>(xz, w_cv, b_cv, xm_bf);
        gemm_bt<<<dim3(1, 16), 256, 0, stream>>>(xm_bf, w_xp, xdbl,
                                                  NTOK, 96, DINNER, 0);
        extract_dt<<<NTOK * DTRANK / 256, 256, 0, stream>>>(xdbl, dtA_bf);
        gemm_bt<<<dim3(16, 16), 256, 0, stream>>>(dtA_bf, w_dt, dtm,
                                                   NTOK, DINNER, DTRANK, 0);
        scan_a<<<GCH * 16, 256, 0, stream>>>(dtm, b_dt, xm_bf, xdbl, al,
                                             h_end, S_chunk);
        scan_b<<<2 * 16 * DINNER / 256, 256, 0, stream>>>(al, S_chunk, h_end, h_in);
        scan_c<<<GCH * 16, 256, 0, stream>>>(dtm, xm_bf, xdbl, al, dskl, xz,
                                             h_in, y_bf);
        gemm_bt<<<dim3(8, 16), 256, 0, stream>>>(y_bf, w_out, x_res,
                                                  NTOK, DMODEL, DINNER, 1);
    }
    ln_kernel<<<NTOK, 256, 0, stream>>>(x_res, ln_g, ln_b, nullptr, outp);
}

// Round 4
// 1135.650 us; speedup vs baseline: 1.7276x; 1.7276x over previous
//
#include <hip/hip_runtime.h>

#define NTOK 2048      // BATCH*SEQ
#define SEQL 1024
#define DMODEL 1024
#define DINNER 2048
#define DSTATE 16
#define DTRANK 64
#define GCH 32         // scan chunks
#define LC 32          // steps per chunk
#define XDS 128        // padded xdbl row stride (96 -> 128)

typedef __attribute__((ext_vector_type(8))) short short8;
typedef __attribute__((ext_vector_type(4))) float float4v;

__device__ __forceinline__ unsigned short f2bf(float f) {
    unsigned u = __float_as_uint(f);
    unsigned r = u + 0x7FFFu + ((u >> 16) & 1u);
    return (unsigned short)(r >> 16);
}
__device__ __forceinline__ float bf2f(unsigned short h) {
    return __uint_as_float(((unsigned)h) << 16);
}

// ---------------- f32 -> bf16 weight conversion (8 elems/thread) ----------------
__global__ __launch_bounds__(256) void f32_to_bf16(
    const float* __restrict__ in, unsigned short* __restrict__ out, int n8) {
    int i = blockIdx.x * 256 + threadIdx.x;
    if (i < n8) {
        float4 a = ((const float4*)in)[2 * i];
        float4 b = ((const float4*)in)[2 * i + 1];
        uint4 v;
        v.x = (unsigned)f2bf(a.x) | ((unsigned)f2bf(a.y) << 16);
        v.y = (unsigned)f2bf(a.z) | ((unsigned)f2bf(a.w) << 16);
        v.z = (unsigned)f2bf(b.x) | ((unsigned)f2bf(b.y) << 16);
        v.w = (unsigned)f2bf(b.z) | ((unsigned)f2bf(b.w) << 16);
        ((uint4*)out)[i] = v;
    }
}

// ---------------- LayerNorm: f32 in; bf16 out (inter-layer) or f32 out (final) ----------------
__global__ __launch_bounds__(256) void ln_kernel(
    const float* __restrict__ x, const float* __restrict__ g,
    const float* __restrict__ b, unsigned short* __restrict__ out_bf,
    float* __restrict__ out_f32) {
    int row = blockIdx.x;
    const float* xr = x + (size_t)row * DMODEL;
    int t = threadIdx.x;
    float4 v = ((const float4*)xr)[t];
    float s  = v.x + v.y + v.z + v.w;
    float ss = v.x*v.x + v.y*v.y + v.z*v.z + v.w*v.w;
    for (int o = 32; o; o >>= 1) { s += __shfl_xor(s, o); ss += __shfl_xor(ss, o); }
    __shared__ float red[8];
    int wv = t >> 6;
    if ((t & 63) == 0) { red[wv * 2] = s; red[wv * 2 + 1] = ss; }
    __syncthreads();
    s  = red[0] + red[2] + red[4] + red[6];
    ss = red[1] + red[3] + red[5] + red[7];
    float mu = s * (1.f / DMODEL);
    float rstd = rsqrtf(ss * (1.f / DMODEL) - mu * mu + 1e-5f);
    float4 gv = ((const float4*)g)[t];
    float4 bv = ((const float4*)b)[t];
    float o0 = (v.x - mu) * rstd * gv.x + bv.x;
    float o1 = (v.y - mu) * rstd * gv.y + bv.y;
    float o2 = (v.z - mu) * rstd * gv.z + bv.z;
    float o3 = (v.w - mu) * rstd * gv.w + bv.w;
    if (out_f32) {
        ((float4*)out_f32)[row * 256 + t] = make_float4(o0, o1, o2, o3);
    } else {
        ((ushort4*)out_bf)[row * 256 + t] =
            make_ushort4(f2bf(o0), f2bf(o1), f2bf(o2), f2bf(o3));
    }
}

// ---------------- GEMM: C[M,N] (f32) = A[M,K] (bf16) * B[N,K]^T (bf16) ----------------
// 128x128 tile, 256 threads (4 waves 2x2), BK=32, double-buffered LDS with
// global_load_lds width=16 staging and raw s_waitcnt(vmcnt)+s_barrier sync
// (a __syncthreads here would drain vmcnt(0) and kill the prefetch overlap).
// All M,N,K multiples of 128/32; Nb = real B-row count (xp GEMM: 96, clamp).
#define BKG 32
__global__ __launch_bounds__(256) void gemm_bt(
    const unsigned short* __restrict__ A, const unsigned short* __restrict__ B,
    float* __restrict__ C, int M, int N, int K, int Nb, int accum) {
    __shared__ __attribute__((aligned(16))) unsigned short As[2][128 * BKG];
    __shared__ __attribute__((aligned(16))) unsigned short Bs[2][128 * BKG];
    int m0 = blockIdx.y * 128, n0 = blockIdx.x * 128;
    int t = threadIdx.x;
    int lane = t & 63, w = t >> 6;
    int wr = (w >> 1) * 64, wc = (w & 1) * 64;
    int tr = lane & 15, quad = lane >> 4;
    int srow = lane >> 2;           // 0..15 within a 16-row chunk
    int scol = (lane & 3) * 8;      // element col 0/8/16/24

    float4v acc[4][4];
    for (int mi = 0; mi < 4; ++mi)
        for (int ni = 0; ni < 4; ++ni)
            acc[mi][ni] = (float4v){0.f, 0.f, 0.f, 0.f};

    auto stage = [&](int kt, int buf) {
        int kbase = kt * BKG;
#pragma unroll
        for (int j = 0; j < 2; ++j) {
            int c = w * 2 + j;                 // chunk 0..7 (16 rows each)
            int arow = m0 + c * 16 + srow;
            const unsigned short* ga = A + (size_t)arow * K + kbase + scol;
            __builtin_amdgcn_global_load_lds(
                (const __attribute__((address_space(1))) void*)ga,
                (__attribute__((address_space(3))) void*)(&As[buf][c * 512]),
                16, 0, 0);
            int brow = n0 + c * 16 + srow;
            if (brow >= Nb) brow = Nb - 1;     // xp GEMM pad clamp
            const unsigned short* gb = B + (size_t)brow * K + kbase + scol;
            __builtin_amdgcn_global_load_lds(
                (const __attribute__((address_space(1))) void*)gb,
                (__attribute__((address_space(3))) void*)(&Bs[buf][c * 512]),
                16, 0, 0);
        }
    };

    int KT = K / BKG;
    stage(0, 0);
    for (int kt = 0; kt < KT; ++kt) {
        int cur = kt & 1;
        bool pf = (kt + 1 < KT);
        if (pf) stage(kt + 1, 1 - cur);
        asm volatile("" ::: "memory");
        // wait: the 4 loads of buf[cur] (older) done; the 4 prefetch stay in flight
        if (pf) __builtin_amdgcn_s_waitcnt(0x0F74);   // vmcnt(4) expcnt(7) lgkm(15)
        else    __builtin_amdgcn_s_waitcnt(0x0F70);   // vmcnt(0)
        __builtin_amdgcn_s_barrier();
        asm volatile("" ::: "memory");
        short8 af[4], bfr[4];
#pragma unroll
        for (int i = 0; i < 4; ++i)
            af[i] = *(const short8*)(&As[cur][(wr + i * 16 + tr) * BKG + quad * 8]);
#pragma unroll
        for (int i = 0; i < 4; ++i)
            bfr[i] = *(const short8*)(&Bs[cur][(wc + i * 16 + tr) * BKG + quad * 8]);
#pragma unroll
        for (int mi = 0; mi < 4; ++mi)
#pragma unroll
            for (int ni = 0; ni < 4; ++ni)
                acc[mi][ni] = __builtin_amdgcn_mfma_f32_16x16x32_bf16(
                    af[mi], bfr[ni], acc[mi][ni], 0, 0, 0);
        asm volatile("" ::: "memory");
        if (pf) __builtin_amdgcn_s_barrier();   // all done reading buf[cur] before it is re-staged
        asm volatile("" ::: "memory");
    }
    // C/D layout (m89-verified): col = lane&15, row = (lane>>4)*4 + reg
    for (int mi = 0; mi < 4; ++mi)
        for (int ni = 0; ni < 4; ++ni) {
            int col = n0 + wc + ni * 16 + tr;
            int rowb = m0 + wr + mi * 16 + quad * 4;
            for (int r = 0; r < 4; ++r) {
                float* pc = C + (size_t)(rowb + r) * N + col;
                if (accum) *pc += acc[mi][ni][r]; else *pc = acc[mi][ni][r];
            }
        }
}

// ---------------- causal depthwise conv(4) + bias + silu -> bf16 ----------------
__global__ __launch_bounds__(256) void conv_silu(
    const float* __restrict__ xz, const float* __restrict__ cw,
    const float* __restrict__ cb, unsigned short* __restrict__ xm_bf) {
    int idx = blockIdx.x * 256 + threadIdx.x;   // NTOK*DINNER
    int c = idx & (DINNER - 1);
    int tk = idx >> 11;
    int l = tk & (SEQL - 1);
    float4 wv = ((const float4*)cw)[c];
    float acc = cb[c];
    const float* base = xz + (size_t)tk * (2 * DINNER) + c;
    if (l >= 3) acc += base[-3 * 2 * DINNER] * wv.x;
    if (l >= 2) acc += base[-2 * 2 * DINNER] * wv.y;
    if (l >= 1) acc += base[-1 * 2 * DINNER] * wv.z;
    acc += base[0] * wv.w;
    float sv = acc / (1.f + expf(-acc));
    xm_bf[idx] = f2bf(sv);
}

// ---------------- extract dt-rank cols of xdbl as bf16 ----------------
__global__ __launch_bounds__(256) void extract_dt(
    const float* __restrict__ xdbl, unsigned short* __restrict__ out) {
    int i = blockIdx.x * 256 + threadIdx.x;   // NTOK*DTRANK
    int tk = i >> 6, r = i & 63;
    out[i] = f2bf(xdbl[(size_t)tk * XDS + r]);
}

// ---------------- scan phase A: local chunk recurrence -> h_end, sum(dt) ----------------
// dtm updated IN PLACE with softplus(dtm + bias).
__global__ __launch_bounds__(256) void scan_a(
    float* __restrict__ dtm, const float* __restrict__ dtb,
    const unsigned short* __restrict__ xm_bf, const float* __restrict__ xdbl,
    const float* __restrict__ A_log,
    float* __restrict__ h_end, float* __restrict__ S_chunk) {
    int bid = blockIdx.x;                 // GCH*2*8 = 512
    int g = bid >> 4, b = (bid >> 3) & 1, cbk = bid & 7;
    int c = cbk * 256 + threadIdx.x;
    __shared__ float Bsh[LC][16];
    for (int r = 0; r < 2; ++r) {
        int e = threadIdx.x + r * 256;
        int li = e >> 4, s = e & 15;
        Bsh[li][s] = xdbl[((size_t)(b * SEQL + g * LC + li)) * XDS + 64 + s];
    }
    __syncthreads();
    float a_l2[16], h[16];
#pragma unroll
    for (int s = 0; s < 16; ++s) {
        a_l2[s] = -expf(A_log[c * 16 + s]) * 1.44269504f;
        h[s] = 0.f;
    }
    float dtbias = dtb[c];
    float S = 0.f;
    int rowbase = b * SEQL + g * LC;
    for (int i = 0; i < LC; ++i) {
        size_t off = (size_t)(rowbase + i) * DINNER + c;
        float xv = dtm[off] + dtbias;
        float dtv = (xv > 15.f) ? xv : log1pf(expf(xv));
        dtm[off] = dtv;
        S += dtv;
        float u = bf2f(xm_bf[off]);
        float bu = dtv * u;
#pragma unroll
        for (int s = 0; s < 16; ++s) {
            float dA = exp2f(dtv * a_l2[s]);
            h[s] = dA * h[s] + Bsh[i][s] * bu;
        }
    }
    int gb = g * 2 + b;
#pragma unroll
    for (int s = 0; s < 16; ++s)
        h_end[((size_t)gb * 16 + s) * DINNER + c] = h[s];
    S_chunk[(size_t)gb * DINNER + c] = S;
}

// ---------------- scan phase B: combine chunks -> h_in per chunk ----------------
__global__ __launch_bounds__(256) void scan_b(
    const float* __restrict__ A_log, const float* __restrict__ S_chunk,
    const float* __restrict__ h_end, float* __restrict__ h_in) {
    int idx = blockIdx.x * 256 + threadIdx.x;   // 2*16*2048 = 65536
    int c = idx & (DINNER - 1);
    int s = (idx >> 11) & 15;
    int b = idx >> 15;
    float a_l2 = -expf(A_log[c * 16 + s]) * 1.44269504f;
    float h = 0.f;
    for (int g = 0; g < GCH; ++g) {
        int gb = g * 2 + b;
        h_in[((size_t)gb * 16 + s) * DINNER + c] = h;
        float P = exp2f(a_l2 * S_chunk[(size_t)gb * DINNER + c]);
        h = P * h + h_end[((size_t)gb * 16 + s) * DINNER + c];
    }
}

// ---------------- scan phase C: seeded recurrence -> y (D-skip + silu(z) fused) ----------------
__global__ __launch_bounds__(256) void scan_c(
    const float* __restrict__ dt_buf, const unsigned short* __restrict__ xm_bf,
    const float* __restrict__ xdbl, const float* __restrict__ A_log,
    const float* __restrict__ D_skip, const float* __restrict__ xz,
    const float* __restrict__ h_in, unsigned short* __restrict__ y_bf) {
    int bid = blockIdx.x;
    int g = bid >> 4, b = (bid >> 3) & 1, cbk = bid & 7;
    int c = cbk * 256 + threadIdx.x;
    __shared__ float BCsh[LC][32];
    for (int r = 0; r < 4; ++r) {
        int e = threadIdx.x + r * 256;
        int li = e >> 5, s = e & 31;
        BCsh[li][s] = xdbl[((size_t)(b * SEQL + g * LC + li)) * XDS + 64 + s];
    }
    __syncthreads();
    int gb = g * 2 + b;
    float a_l2[16], h[16];
#pragma unroll
    for (int s = 0; s < 16; ++s) {
        a_l2[s] = -expf(A_log[c * 16 + s]) * 1.44269504f;
        h[s] = h_in[((size_t)gb * 16 + s) * DINNER + c];
    }
    float dsk = D_skip[c];
    int rowbase = b * SEQL + g * LC;
    for (int i = 0; i < LC; ++i) {
        size_t off = (size_t)(rowbase + i) * DINNER + c;
        float dtv = dt_buf[off];
        float u = bf2f(xm_bf[off]);
        float bu = dtv * u;
        float y = 0.f;
#pragma unroll
        for (int s = 0; s < 16; ++s) {
            float dA = exp2f(dtv * a_l2[s]);
            h[s] = dA * h[s] + BCsh[i][s] * bu;
            y += h[s] * BCsh[i][16 + s];
        }
        y += u * dsk;
        float zv = xz[(size_t)(rowbase + i) * (2 * DINNER) + DINNER + c];
        y *= zv / (1.f + expf(-zv));
        y_bf[off] = f2bf(y);
    }
}

extern "C" void kernel_launch(void* const* d_in, const int* in_sizes, int n_in,
                              void* d_out, int out_size, void* d_ws, size_t ws_size,
                              hipStream_t stream) {
    const float* x_in   = (const float*)d_in[0];
    const float* in_w   = (const float*)d_in[1];
    const float* conv_w = (const float*)d_in[2];
    const float* conv_b = (const float*)d_in[3];
    const float* xp_w   = (const float*)d_in[4];
    const float* dt_w   = (const float*)d_in[5];
    const float* dt_b   = (const float*)d_in[6];
    const float* A_logp = (const float*)d_in[7];
    const float* Dsk    = (const float*)d_in[8];
    const float* out_w  = (const float*)d_in[9];
    const float* ln_g   = (const float*)d_in[10];
    const float* ln_b   = (const float*)d_in[11];
    float* outp = (float*)d_out;           // reference output dtype: float32

    char* p = (char*)d_ws;
    auto alloc = [&](size_t bytes) {
        void* r = (void*)p;
        p += (bytes + 255) & ~(size_t)255;
        return r;
    };
    float* x_res  = (float*)alloc((size_t)NTOK * DMODEL * 4);
    unsigned short* xn_bf = (unsigned short*)alloc((size_t)NTOK * DMODEL * 2);
    float* xz     = (float*)alloc((size_t)NTOK * 2 * DINNER * 4);
    unsigned short* xm_bf = (unsigned short*)alloc((size_t)NTOK * DINNER * 2);
    float* xdbl   = (float*)alloc((size_t)NTOK * XDS * 4);
    unsigned short* dtA_bf = (unsigned short*)alloc((size_t)NTOK * DTRANK * 2);
    float* dtm    = (float*)alloc((size_t)NTOK * DINNER * 4);   // holds dt after scan_a
    unsigned short* y_bf = (unsigned short*)alloc((size_t)NTOK * DINNER * 2);
    float* h_end  = (float*)alloc((size_t)GCH * 2 * 16 * DINNER * 4);
    float* h_in   = (float*)alloc((size_t)GCH * 2 * 16 * DINNER * 4);
    float* S_chunk = (float*)alloc((size_t)GCH * 2 * DINNER * 4);
    // bf16 weight copies
    int n_inw  = 4 * 2 * DINNER * DMODEL;   // 16.8M
    int n_xpw  = 4 * 96 * DINNER;           // 0.79M
    int n_dtw  = 4 * DINNER * DTRANK;       // 0.52M
    int n_outw = 4 * DMODEL * DINNER;       // 8.4M
    unsigned short* wbf_in  = (unsigned short*)alloc((size_t)n_inw * 2);
    unsigned short* wbf_xp  = (unsigned short*)alloc((size_t)n_xpw * 2);
    unsigned short* wbf_dt  = (unsigned short*)alloc((size_t)n_dtw * 2);
    unsigned short* wbf_out = (unsigned short*)alloc((size_t)n_outw * 2);

    f32_to_bf16<<<(n_inw / 8 + 255) / 256, 256, 0, stream>>>(in_w, wbf_in, n_inw / 8);
    f32_to_bf16<<<(n_xpw / 8 + 255) / 256, 256, 0, stream>>>(xp_w, wbf_xp, n_xpw / 8);
    f32_to_bf16<<<(n_dtw / 8 + 255) / 256, 256, 0, stream>>>(dt_w, wbf_dt, n_dtw / 8);
    f32_to_bf16<<<(n_outw / 8 + 255) / 256, 256, 0, stream>>>(out_w, wbf_out, n_outw / 8);

    // residual stream init: x_res = x (f32 copy, d2d)
    hipMemcpyAsync(x_res, x_in, (size_t)NTOK * DMODEL * 4,
                   hipMemcpyDeviceToDevice, stream);

    for (int L = 0; L < 4; ++L) {
        const unsigned short* w_in  = wbf_in  + (size_t)L * 2 * DINNER * DMODEL;
        const float*          w_cv  = conv_w  + (size_t)L * DINNER * 4;
        const float*          b_cv  = conv_b  + (size_t)L * DINNER;
        const unsigned short* w_xp  = wbf_xp  + (size_t)L * 96 * DINNER;
        const unsigned short* w_dt  = wbf_dt  + (size_t)L * DINNER * DTRANK;
        const float*          b_dt  = dt_b    + (size_t)L * DINNER;
        const float*          al    = A_logp  + (size_t)L * DINNER * DSTATE;
        const float*          dskl  = Dsk     + (size_t)L * DINNER;
        const unsigned short* w_out = wbf_out + (size_t)L * DMODEL * DINNER;

        ln_kernel<<<NTOK, 256, 0, stream>>>(x_res, ln_g, ln_b, xn_bf, nullptr);
        gemm_bt<<<dim3(32, 16), 256, 0, stream>>>(xn_bf, w_in, xz,
                                                   NTOK, 2 * DINNER, DMODEL, 2 * DINNER, 0);
        conv_silu<<<NTOK * DINNER / 256, 256, 0, stream>>>(xz, w_cv, b_cv, xm_bf);
        gemm_bt<<<dim3(1, 16), 256, 0, stream>>>(xm_bf, w_xp, xdbl,
                                                  NTOK, XDS, DINNER, 96, 0);
        extract_dt<<<NTOK * DTRANK / 256, 256, 0, stream>>>(xdbl, dtA_bf);
        gemm_bt<<<dim3(16, 16), 256, 0, stream>>>(dtA_bf, w_dt, dtm,
                                                   NTOK, DINNER, DTRANK, DINNER, 0);
        scan_a<<<GCH * 16, 256, 0, stream>>>(dtm, b_dt, xm_bf, xdbl, al,
                                             h_end, S_chunk);
        scan_b<<<2 * 16 * DINNER / 256, 256, 0, stream>>>(al, S_chunk, h_end, h_in);
        scan_c<<<GCH * 16, 256, 0, stream>>>(dtm, xm_bf, xdbl, al, dskl, xz,
                                             h_in, y_bf);
        gemm_bt<<<dim3(8, 16), 256, 0, stream>>>(y_bf, w_out, x_res,
                                                  NTOK, DMODEL, DINNER, DMODEL, 1);
    }
    ln_kernel<<<NTOK, 256, 0, stream>>>(x_res, ln_g, ln_b, nullptr, outp);
}

// Round 5
// 1028.202 us; speedup vs baseline: 1.9081x; 1.1045x over previous
//
#include <hip/hip_runtime.h>

#define NTOK 2048      // BATCH*SEQ
#define SEQL 1024
#define DMODEL 1024
#define DINNER 2048
#define DSTATE 16
#define DTRANK 64
#define GCH 64         // scan chunks
#define LC 16          // steps per chunk
#define XDS 128        // padded xdbl row stride (96 -> 128)

typedef __attribute__((ext_vector_type(8))) short short8;
typedef __attribute__((ext_vector_type(4))) float float4v;

__device__ __forceinline__ unsigned short f2bf(float f) {
    unsigned u = __float_as_uint(f);
    unsigned r = u + 0x7FFFu + ((u >> 16) & 1u);
    return (unsigned short)(r >> 16);
}
__device__ __forceinline__ float bf2f(unsigned short h) {
    return __uint_as_float(((unsigned)h) << 16);
}

// ---------------- f32 -> bf16 weight conversion (8 elems/thread) ----------------
__global__ __launch_bounds__(256) void f32_to_bf16(
    const float* __restrict__ in, unsigned short* __restrict__ out, int n8) {
    int i = blockIdx.x * 256 + threadIdx.x;
    if (i < n8) {
        float4 a = ((const float4*)in)[2 * i];
        float4 b = ((const float4*)in)[2 * i + 1];
        uint4 v;
        v.x = (unsigned)f2bf(a.x) | ((unsigned)f2bf(a.y) << 16);
        v.y = (unsigned)f2bf(a.z) | ((unsigned)f2bf(a.w) << 16);
        v.z = (unsigned)f2bf(b.x) | ((unsigned)f2bf(b.y) << 16);
        v.w = (unsigned)f2bf(b.z) | ((unsigned)f2bf(b.w) << 16);
        ((uint4*)out)[i] = v;
    }
}

__global__ __launch_bounds__(256) void zero_f32(float* __restrict__ p, int n4) {
    int i = blockIdx.x * 256 + threadIdx.x;
    if (i < n4) ((float4*)p)[i] = make_float4(0.f, 0.f, 0.f, 0.f);
}

// ---------------- LayerNorm: f32 in; bf16 out (inter-layer) or f32 out (final) ----------------
__global__ __launch_bounds__(256) void ln_kernel(
    const float* __restrict__ x, const float* __restrict__ g,
    const float* __restrict__ b, unsigned short* __restrict__ out_bf,
    float* __restrict__ out_f32) {
    int row = blockIdx.x;
    const float* xr = x + (size_t)row * DMODEL;
    int t = threadIdx.x;
    float4 v = ((const float4*)xr)[t];
    float s  = v.x + v.y + v.z + v.w;
    float ss = v.x*v.x + v.y*v.y + v.z*v.z + v.w*v.w;
    for (int o = 32; o; o >>= 1) { s += __shfl_xor(s, o); ss += __shfl_xor(ss, o); }
    __shared__ float red[8];
    int wv = t >> 6;
    if ((t & 63) == 0) { red[wv * 2] = s; red[wv * 2 + 1] = ss; }
    __syncthreads();
    s  = red[0] + red[2] + red[4] + red[6];
    ss = red[1] + red[3] + red[5] + red[7];
    float mu = s * (1.f / DMODEL);
    float rstd = rsqrtf(ss * (1.f / DMODEL) - mu * mu + 1e-5f);
    float4 gv = ((const float4*)g)[t];
    float4 bv = ((const float4*)b)[t];
    float o0 = (v.x - mu) * rstd * gv.x + bv.x;
    float o1 = (v.y - mu) * rstd * gv.y + bv.y;
    float o2 = (v.z - mu) * rstd * gv.z + bv.z;
    float o3 = (v.w - mu) * rstd * gv.w + bv.w;
    if (out_f32) {
        ((float4*)out_f32)[row * 256 + t] = make_float4(o0, o1, o2, o3);
    } else {
        ((ushort4*)out_bf)[row * 256 + t] =
            make_ushort4(f2bf(o0), f2bf(o1), f2bf(o2), f2bf(o3));
    }
}

// ---------------- GEMM: C[M,N] = A[M,K](bf16) * B[N,K]^T(bf16) ----------------
// 128x128 tile, 256 threads (4 waves 2x2), BK=32, 3-deep LDS pipeline with
// global_load_lds(16B) and raw s_waitcnt(vmcnt)+s_barrier (NOT __syncthreads:
// that drains vmcnt(0) and kills prefetch). Split-K via gridDim.z.
// Modes: 0 = f32 store; 1 = f32 atomicAdd (split-K / accumulate);
//        2 = bf16 store; 3 = f32 store of softplus(acc + bias[col]).
#define BKG 32
__global__ __launch_bounds__(256) void gemm_bt(
    const unsigned short* __restrict__ A, const unsigned short* __restrict__ B,
    void* __restrict__ Cv, const float* __restrict__ bias,
    int M, int N, int K, int Nb, int mode) {
    __shared__ __attribute__((aligned(16))) unsigned short As[3][128 * BKG];
    __shared__ __attribute__((aligned(16))) unsigned short Bs[3][128 * BKG];
    int m0 = blockIdx.y * 128, n0 = blockIdx.x * 128;
    int Klocal = K / gridDim.z;
    int kstart = blockIdx.z * Klocal;
    int t = threadIdx.x;
    int lane = t & 63, w = t >> 6;
    int wr = (w >> 1) * 64, wc = (w & 1) * 64;
    int tr = lane & 15, quad = lane >> 4;
    int srow = lane >> 2;           // 0..15 within a 16-row chunk
    int scol = (lane & 3) * 8;      // element col 0/8/16/24

    float4v acc[4][4];
    for (int mi = 0; mi < 4; ++mi)
        for (int ni = 0; ni < 4; ++ni)
            acc[mi][ni] = (float4v){0.f, 0.f, 0.f, 0.f};

    auto stage = [&](int kt, int buf) {
        int kbase = kstart + kt * BKG;
#pragma unroll
        for (int j = 0; j < 2; ++j) {
            int c = w * 2 + j;                 // chunk 0..7 (16 rows each)
            int arow = m0 + c * 16 + srow;
            const unsigned short* ga = A + (size_t)arow * K + kbase + scol;
            __builtin_amdgcn_global_load_lds(
                (const __attribute__((address_space(1))) void*)ga,
                (__attribute__((address_space(3))) void*)(&As[buf][c * 512]),
                16, 0, 0);
            int brow = n0 + c * 16 + srow;
            if (brow >= Nb) brow = Nb - 1;     // xp GEMM pad clamp
            const unsigned short* gb = B + (size_t)brow * K + kbase + scol;
            __builtin_amdgcn_global_load_lds(
                (const __attribute__((address_space(1))) void*)gb,
                (__attribute__((address_space(3))) void*)(&Bs[buf][c * 512]),
                16, 0, 0);
        }
    };

    int KT = Klocal / BKG;
    stage(0, 0);
    if (KT > 1) stage(1, 1);
    for (int kt = 0; kt < KT; ++kt) {
        int cur = kt % 3;
        if (kt + 2 < KT) stage(kt + 2, (kt + 2) % 3);
        asm volatile("" ::: "memory");
        int nleft = KT - kt - 1;
        if (nleft >= 2)      __builtin_amdgcn_s_waitcnt(0x0F78);  // vmcnt(8)
        else if (nleft == 1) __builtin_amdgcn_s_waitcnt(0x0F74);  // vmcnt(4)
        else                 __builtin_amdgcn_s_waitcnt(0x0F70);  // vmcnt(0)
        __builtin_amdgcn_s_barrier();
        asm volatile("" ::: "memory");
        short8 af[4], bfr[4];
#pragma unroll
        for (int i = 0; i < 4; ++i)
            af[i] = *(const short8*)(&As[cur][(wr + i * 16 + tr) * BKG + quad * 8]);
#pragma unroll
        for (int i = 0; i < 4; ++i)
            bfr[i] = *(const short8*)(&Bs[cur][(wc + i * 16 + tr) * BKG + quad * 8]);
#pragma unroll
        for (int mi = 0; mi < 4; ++mi)
#pragma unroll
            for (int ni = 0; ni < 4; ++ni)
                acc[mi][ni] = __builtin_amdgcn_mfma_f32_16x16x32_bf16(
                    af[mi], bfr[ni], acc[mi][ni], 0, 0, 0);
        asm volatile("" ::: "memory");
        __builtin_amdgcn_s_barrier();   // protect buffer about to be re-staged
        asm volatile("" ::: "memory");
    }
    // C/D layout (m89-verified): col = lane&15, row = (lane>>4)*4 + reg
    for (int mi = 0; mi < 4; ++mi)
        for (int ni = 0; ni < 4; ++ni) {
            int col = n0 + wc + ni * 16 + tr;
            int rowb = m0 + wr + mi * 16 + quad * 4;
            for (int r = 0; r < 4; ++r) {
                size_t off = (size_t)(rowb + r) * N + col;
                float val = acc[mi][ni][r];
                if (mode == 0) {
                    ((float*)Cv)[off] = val;
                } else if (mode == 1) {
                    atomicAdd((float*)Cv + off, val);
                } else if (mode == 2) {
                    ((unsigned short*)Cv)[off] = f2bf(val);
                } else {
                    float v2 = val + bias[col];
                    ((float*)Cv)[off] = (v2 > 15.f) ? v2 : log1pf(expf(v2));
                }
            }
        }
}

// ---------------- causal depthwise conv(4) + bias + silu; bf16 in -> bf16 out ----------------
__global__ __launch_bounds__(256) void conv_silu(
    const unsigned short* __restrict__ xz, const float* __restrict__ cw,
    const float* __restrict__ cb, unsigned short* __restrict__ xm_bf) {
    int i = blockIdx.x * 256 + threadIdx.x;     // NTOK*DINNER/4
    int c4 = (i * 4) & (DINNER - 1);
    int tk = (i * 4) >> 11;
    int l = tk & (SEQL - 1);
    float4 w0 = ((const float4*)cw)[c4 + 0];
    float4 w1 = ((const float4*)cw)[c4 + 1];
    float4 w2 = ((const float4*)cw)[c4 + 2];
    float4 w3 = ((const float4*)cw)[c4 + 3];
    float4 a = ((const float4*)cb)[c4 >> 2];
    const unsigned short* base = xz + (size_t)tk * (2 * DINNER) + c4;
    ushort4 v;
    if (l >= 3) {
        v = *(const ushort4*)(base - 3 * 2 * DINNER);
        a.x += bf2f(v.x) * w0.x; a.y += bf2f(v.y) * w1.x;
        a.z += bf2f(v.z) * w2.x; a.w += bf2f(v.w) * w3.x;
    }
    if (l >= 2) {
        v = *(const ushort4*)(base - 2 * 2 * DINNER);
        a.x += bf2f(v.x) * w0.y; a.y += bf2f(v.y) * w1.y;
        a.z += bf2f(v.z) * w2.y; a.w += bf2f(v.w) * w3.y;
    }
    if (l >= 1) {
        v = *(const ushort4*)(base - 1 * 2 * DINNER);
        a.x += bf2f(v.x) * w0.z; a.y += bf2f(v.y) * w1.z;
        a.z += bf2f(v.z) * w2.z; a.w += bf2f(v.w) * w3.z;
    }
    v = *(const ushort4*)(base);
    a.x += bf2f(v.x) * w0.w; a.y += bf2f(v.y) * w1.w;
    a.z += bf2f(v.z) * w2.w; a.w += bf2f(v.w) * w3.w;
    float s0 = a.x / (1.f + expf(-a.x));
    float s1 = a.y / (1.f + expf(-a.y));
    float s2 = a.z / (1.f + expf(-a.z));
    float s3 = a.w / (1.f + expf(-a.w));
    ((ushort4*)xm_bf)[i] = make_ushort4(f2bf(s0), f2bf(s1), f2bf(s2), f2bf(s3));
}

// ---------------- extract dt-rank cols of xdbl as bf16 ----------------
__global__ __launch_bounds__(256) void extract_dt(
    const float* __restrict__ xdbl, unsigned short* __restrict__ out) {
    int i = blockIdx.x * 256 + threadIdx.x;   // NTOK*DTRANK
    int tk = i >> 6, r = i & 63;
    out[i] = f2bf(xdbl[(size_t)tk * XDS + r]);
}

// ---------------- scan phase A: local chunk recurrence -> h_end, sum(dt) ----------------
// dt already softplus'ed (fused into dt GEMM epilogue).
__global__ __launch_bounds__(256) void scan_a(
    const float* __restrict__ dt, const unsigned short* __restrict__ xm_bf,
    const float* __restrict__ xdbl, const float* __restrict__ A_log,
    float* __restrict__ h_end, float* __restrict__ S_chunk) {
    int bid = blockIdx.x;                 // GCH*2*8 = 1024
    int g = bid >> 4, b = (bid >> 3) & 1, cbk = bid & 7;
    int c = cbk * 256 + threadIdx.x;
    __shared__ float Bsh[LC][16];
    {
        int li = threadIdx.x >> 4, s = threadIdx.x & 15;
        Bsh[li][s] = xdbl[((size_t)(b * SEQL + g * LC + li)) * XDS + 64 + s];
    }
    __syncthreads();
    float a_l2[16], h[16];
#pragma unroll
    for (int s = 0; s < 16; ++s) {
        a_l2[s] = -expf(A_log[c * 16 + s]) * 1.44269504f;
        h[s] = 0.f;
    }
    float S = 0.f;
    int rowbase = b * SEQL + g * LC;
    for (int i = 0; i < LC; ++i) {
        size_t off = (size_t)(rowbase + i) * DINNER + c;
        float dtv = dt[off];
        S += dtv;
        float u = bf2f(xm_bf[off]);
        float bu = dtv * u;
#pragma unroll
        for (int s = 0; s < 16; ++s) {
            float dA = exp2f(dtv * a_l2[s]);
            h[s] = dA * h[s] + Bsh[i][s] * bu;
        }
    }
    int gb = g * 2 + b;
#pragma unroll
    for (int s = 0; s < 16; ++s)
        h_end[((size_t)gb * 16 + s) * DINNER + c] = h[s];
    S_chunk[(size_t)gb * DINNER + c] = S;
}

// ---------------- scan phase B: combine chunks -> h_in per chunk ----------------
__global__ __launch_bounds__(256) void scan_b(
    const float* __restrict__ A_log, const float* __restrict__ S_chunk,
    const float* __restrict__ h_end, float* __restrict__ h_in) {
    int idx = blockIdx.x * 256 + threadIdx.x;   // 2*16*2048 = 65536
    int c = idx & (DINNER - 1);
    int s = (idx >> 11) & 15;
    int b = idx >> 15;
    float a_l2 = -expf(A_log[c * 16 + s]) * 1.44269504f;
    float h = 0.f;
    for (int g = 0; g < GCH; ++g) {
        int gb = g * 2 + b;
        h_in[((size_t)gb * 16 + s) * DINNER + c] = h;
        float P = exp2f(a_l2 * S_chunk[(size_t)gb * DINNER + c]);
        h = P * h + h_end[((size_t)gb * 16 + s) * DINNER + c];
    }
}

// ---------------- scan phase C: seeded recurrence -> y (D-skip + silu(z) fused) ----------------
__global__ __launch_bounds__(256) void scan_c(
    const float* __restrict__ dt, const unsigned short* __restrict__ xm_bf,
    const float* __restrict__ xdbl, const float* __restrict__ A_log,
    const float* __restrict__ D_skip, const unsigned short* __restrict__ xz,
    const float* __restrict__ h_in, unsigned short* __restrict__ y_bf) {
    int bid = blockIdx.x;                 // 1024
    int g = bid >> 4, b = (bid >> 3) & 1, cbk = bid & 7;
    int c = cbk * 256 + threadIdx.x;
    __shared__ float BCsh[LC][32];
    for (int r = 0; r < 2; ++r) {
        int e = threadIdx.x + r * 256;
        int li = e >> 5, s = e & 31;
        BCsh[li][s] = xdbl[((size_t)(b * SEQL + g * LC + li)) * XDS + 64 + s];
    }
    __syncthreads();
    int gb = g * 2 + b;
    float a_l2[16], h[16];
#pragma unroll
    for (int s = 0; s < 16; ++s) {
        a_l2[s] = -expf(A_log[c * 16 + s]) * 1.44269504f;
        h[s] = h_in[((size_t)gb * 16 + s) * DINNER + c];
    }
    float dsk = D_skip[c];
    int rowbase = b * SEQL + g * LC;
    for (int i = 0; i < LC; ++i) {
        size_t off = (size_t)(rowbase + i) * DINNER + c;
        float dtv = dt[off];
        float u = bf2f(xm_bf[off]);
        float bu = dtv * u;
        float y = 0.f;
#pragma unroll
        for (int s = 0; s < 16; ++s) {
            float dA = exp2f(dtv * a_l2[s]);
            h[s] = dA * h[s] + BCsh[i][s] * bu;
            y += h[s] * BCsh[i][16 + s];
        }
        y += u * dsk;
        float zv = bf2f(xz[(size_t)(rowbase + i) * (2 * DINNER) + DINNER + c]);
        y *= zv / (1.f + expf(-zv));
        y_bf[off] = f2bf(y);
    }
}

extern "C" void kernel_launch(void* const* d_in, const int* in_sizes, int n_in,
                              void* d_out, int out_size, void* d_ws, size_t ws_size,
                              hipStream_t stream) {
    const float* x_in   = (const float*)d_in[0];
    const float* in_w   = (const float*)d_in[1];
    const float* conv_w = (const float*)d_in[2];
    const float* conv_b = (const float*)d_in[3];
    const float* xp_w   = (const float*)d_in[4];
    const float* dt_w   = (const float*)d_in[5];
    const float* dt_b   = (const float*)d_in[6];
    const float* A_logp = (const float*)d_in[7];
    const float* Dsk    = (const float*)d_in[8];
    const float* out_w  = (const float*)d_in[9];
    const float* ln_g   = (const float*)d_in[10];
    const float* ln_b   = (const float*)d_in[11];
    float* outp = (float*)d_out;

    char* p = (char*)d_ws;
    auto alloc = [&](size_t bytes) {
        void* r = (void*)p;
        p += (bytes + 255) & ~(size_t)255;
        return r;
    };
    float* x_res  = (float*)alloc((size_t)NTOK * DMODEL * 4);
    unsigned short* xn_bf = (unsigned short*)alloc((size_t)NTOK * DMODEL * 2);
    unsigned short* xz_bf = (unsigned short*)alloc((size_t)NTOK * 2 * DINNER * 2);
    unsigned short* xm_bf = (unsigned short*)alloc((size_t)NTOK * DINNER * 2);
    float* xdbl   = (float*)alloc((size_t)NTOK * XDS * 4);
    unsigned short* dtA_bf = (unsigned short*)alloc((size_t)NTOK * DTRANK * 2);
    float* dtm    = (float*)alloc((size_t)NTOK * DINNER * 4);   // softplus(dt) from GEMM
    unsigned short* y_bf = (unsigned short*)alloc((size_t)NTOK * DINNER * 2);
    float* h_end  = (float*)alloc((size_t)GCH * 2 * 16 * DINNER * 4);
    float* h_in   = (float*)alloc((size_t)GCH * 2 * 16 * DINNER * 4);
    float* S_chunk = (float*)alloc((size_t)GCH * 2 * DINNER * 4);
    // bf16 weight copies
    int n_inw  = 4 * 2 * DINNER * DMODEL;
    int n_xpw  = 4 * 96 * DINNER;
    int n_dtw  = 4 * DINNER * DTRANK;
    int n_outw = 4 * DMODEL * DINNER;
    unsigned short* wbf_in  = (unsigned short*)alloc((size_t)n_inw * 2);
    unsigned short* wbf_xp  = (unsigned short*)alloc((size_t)n_xpw * 2);
    unsigned short* wbf_dt  = (unsigned short*)alloc((size_t)n_dtw * 2);
    unsigned short* wbf_out = (unsigned short*)alloc((size_t)n_outw * 2);

    f32_to_bf16<<<(n_inw / 8 + 255) / 256, 256, 0, stream>>>(in_w, wbf_in, n_inw / 8);
    f32_to_bf16<<<(n_xpw / 8 + 255) / 256, 256, 0, stream>>>(xp_w, wbf_xp, n_xpw / 8);
    f32_to_bf16<<<(n_dtw / 8 + 255) / 256, 256, 0, stream>>>(dt_w, wbf_dt, n_dtw / 8);
    f32_to_bf16<<<(n_outw / 8 + 255) / 256, 256, 0, stream>>>(out_w, wbf_out, n_outw / 8);

    hipMemcpyAsync(x_res, x_in, (size_t)NTOK * DMODEL * 4,
                   hipMemcpyDeviceToDevice, stream);

    for (int L = 0; L < 4; ++L) {
        const unsigned short* w_in  = wbf_in  + (size_t)L * 2 * DINNER * DMODEL;
        const float*          w_cv  = conv_w  + (size_t)L * DINNER * 4;
        const float*          b_cv  = conv_b  + (size_t)L * DINNER;
        const unsigned short* w_xp  = wbf_xp  + (size_t)L * 96 * DINNER;
        const unsigned short* w_dt  = wbf_dt  + (size_t)L * DINNER * DTRANK;
        const float*          b_dt  = dt_b    + (size_t)L * DINNER;
        const float*          al    = A_logp  + (size_t)L * DINNER * DSTATE;
        const float*          dskl  = Dsk     + (size_t)L * DINNER;
        const unsigned short* w_out = wbf_out + (size_t)L * DMODEL * DINNER;

        ln_kernel<<<NTOK, 256, 0, stream>>>(x_res, ln_g, ln_b, xn_bf, nullptr);
        // in_proj: [2048 x 4096 x 1024], bf16 epilogue
        gemm_bt<<<dim3(32, 16, 1), 256, 0, stream>>>(
            xn_bf, w_in, xz_bf, nullptr, NTOK, 2 * DINNER, DMODEL, 2 * DINNER, 2);
        conv_silu<<<NTOK * DINNER / 1024, 256, 0, stream>>>(xz_bf, w_cv, b_cv, xm_bf);
        // x_proj: [2048 x 128(96) x 2048], split-K 16, atomic into zeroed xdbl
        zero_f32<<<NTOK * XDS / 4 / 256, 256, 0, stream>>>(xdbl, NTOK * XDS / 4);
        gemm_bt<<<dim3(1, 16, 16), 256, 0, stream>>>(
            xm_bf, w_xp, xdbl, nullptr, NTOK, XDS, DINNER, 96, 1);
        extract_dt<<<NTOK * DTRANK / 256, 256, 0, stream>>>(xdbl, dtA_bf);
        // dt_proj: [2048 x 2048 x 64], fused bias+softplus epilogue
        gemm_bt<<<dim3(16, 16, 1), 256, 0, stream>>>(
            dtA_bf, w_dt, dtm, b_dt, NTOK, DINNER, DTRANK, DINNER, 3);
        scan_a<<<GCH * 16, 256, 0, stream>>>(dtm, xm_bf, xdbl, al, h_end, S_chunk);
        scan_b<<<2 * 16 * DINNER / 256, 256, 0, stream>>>(al, S_chunk, h_end, h_in);
        scan_c<<<GCH * 16, 256, 0, stream>>>(dtm, xm_bf, xdbl, al, dskl, xz_bf,
                                             h_in, y_bf);
        // out_proj: [2048 x 1024 x 2048], split-K 4, atomic accumulate into x_res
        gemm_bt<<<dim3(8, 16, 4), 256, 0, stream>>>(
            y_bf, w_out, x_res, nullptr, NTOK, DMODEL, DINNER, DMODEL, 1);
    }
    ln_kernel<<<NTOK, 256, 0, stream>>>(x_res, ln_g, ln_b, nullptr, outp);
}

// Round 6
// 966.185 us; speedup vs baseline: 2.0306x; 1.0642x over previous
//
#include <hip/hip_runtime.h>

#define NTOK 2048      // BATCH*SEQ
#define SEQL 1024
#define DMODEL 1024
#define DINNER 2048
#define DSTATE 16
#define DTRANK 64
#define GCH 64         // scan chunks
#define LC 16          // steps per chunk
#define XDS 128        // padded xdbl row stride (96 -> 128)

typedef __attribute__((ext_vector_type(8))) short short8;
typedef __attribute__((ext_vector_type(4))) float float4v;

__device__ __forceinline__ unsigned short f2bf(float f) {
    unsigned u = __float_as_uint(f);
    unsigned r = u + 0x7FFFu + ((u >> 16) & 1u);
    return (unsigned short)(r >> 16);
}
__device__ __forceinline__ float bf2f(unsigned short h) {
    return __uint_as_float(((unsigned)h) << 16);
}

// ---------------- f32 -> bf16 weight conversion (8 elems/thread) ----------------
__global__ __launch_bounds__(256) void f32_to_bf16(
    const float* __restrict__ in, unsigned short* __restrict__ out, int n8) {
    int i = blockIdx.x * 256 + threadIdx.x;
    if (i < n8) {
        float4 a = ((const float4*)in)[2 * i];
        float4 b = ((const float4*)in)[2 * i + 1];
        uint4 v;
        v.x = (unsigned)f2bf(a.x) | ((unsigned)f2bf(a.y) << 16);
        v.y = (unsigned)f2bf(a.z) | ((unsigned)f2bf(a.w) << 16);
        v.z = (unsigned)f2bf(b.x) | ((unsigned)f2bf(b.y) << 16);
        v.w = (unsigned)f2bf(b.z) | ((unsigned)f2bf(b.w) << 16);
        ((uint4*)out)[i] = v;
    }
}

__global__ __launch_bounds__(256) void zero_f32(float* __restrict__ p, int n4) {
    int i = blockIdx.x * 256 + threadIdx.x;
    if (i < n4) ((float4*)p)[i] = make_float4(0.f, 0.f, 0.f, 0.f);
}

// ---------------- LayerNorm: f32 in; bf16 out (inter-layer) or f32 out (final) ----------------
__global__ __launch_bounds__(256) void ln_kernel(
    const float* __restrict__ x, const float* __restrict__ g,
    const float* __restrict__ b, unsigned short* __restrict__ out_bf,
    float* __restrict__ out_f32) {
    int row = blockIdx.x;
    const float* xr = x + (size_t)row * DMODEL;
    int t = threadIdx.x;
    float4 v = ((const float4*)xr)[t];
    float s  = v.x + v.y + v.z + v.w;
    float ss = v.x*v.x + v.y*v.y + v.z*v.z + v.w*v.w;
    for (int o = 32; o; o >>= 1) { s += __shfl_xor(s, o); ss += __shfl_xor(ss, o); }
    __shared__ float red[8];
    int wv = t >> 6;
    if ((t & 63) == 0) { red[wv * 2] = s; red[wv * 2 + 1] = ss; }
    __syncthreads();
    s  = red[0] + red[2] + red[4] + red[6];
    ss = red[1] + red[3] + red[5] + red[7];
    float mu = s * (1.f / DMODEL);
    float rstd = rsqrtf(ss * (1.f / DMODEL) - mu * mu + 1e-5f);
    float4 gv = ((const float4*)g)[t];
    float4 bv = ((const float4*)b)[t];
    float o0 = (v.x - mu) * rstd * gv.x + bv.x;
    float o1 = (v.y - mu) * rstd * gv.y + bv.y;
    float o2 = (v.z - mu) * rstd * gv.z + bv.z;
    float o3 = (v.w - mu) * rstd * gv.w + bv.w;
    if (out_f32) {
        ((float4*)out_f32)[row * 256 + t] = make_float4(o0, o1, o2, o3);
    } else {
        ((ushort4*)out_bf)[row * 256 + t] =
            make_ushort4(f2bf(o0), f2bf(o1), f2bf(o2), f2bf(o3));
    }
}

// ---------------- GEMM: C[M,N] = A[M,K](bf16) * B[N,K]^T(bf16) ----------------
// 128x64 tile, 256 threads = 4 waves stacked on M (each wave 32x64 -> 2x4 MFMA
// tiles). Depth-3 LDS pipeline (36 KB -> 4 blocks/CU), global_load_lds(16B),
// raw s_waitcnt(vmcnt)+s_barrier (NOT __syncthreads: drains vmcnt(0)).
// LDS 16B-units XOR-swizzled (q' = q ^ ((row>>1)&3)) -> conflict-free b128 reads.
// Split-K via gridDim.z. Modes: 1 = f32 atomicAdd; 2 = bf16 store;
// 3 = bf16 store of softplus(acc + bias[col]).
#define BKG 32
__global__ __launch_bounds__(256) void gemm64(
    const unsigned short* __restrict__ A, const unsigned short* __restrict__ B,
    void* __restrict__ Cv, const float* __restrict__ bias,
    int M, int N, int K, int Nb, int mode) {
    __shared__ __attribute__((aligned(16))) unsigned short As[3][128 * BKG];
    __shared__ __attribute__((aligned(16))) unsigned short Bs[3][64 * BKG];
    int m0 = blockIdx.y * 128, n0 = blockIdx.x * 64;
    int Klocal = K / gridDim.z;
    int kstart = blockIdx.z * Klocal;
    int t = threadIdx.x;
    int lane = t & 63, w = t >> 6;
    int tr = lane & 15, quad = lane >> 4;
    int r_l = lane >> 2;                           // row within 16-row chunk
    int q_l = (lane & 3) ^ ((lane >> 3) & 3);      // swizzled 16B-unit
    int col_l = q_l * 8;                           // element col within BK

    float4v acc[2][4];
    for (int mi = 0; mi < 2; ++mi)
        for (int ni = 0; ni < 4; ++ni)
            acc[mi][ni] = (float4v){0.f, 0.f, 0.f, 0.f};

    auto stage = [&](int kt, int buf) {
        int kbase = kstart + kt * BKG;
#pragma unroll
        for (int j = 0; j < 2; ++j) {
            int c = w * 2 + j;                     // A chunk 0..7
            const unsigned short* ga = A + (size_t)(m0 + c * 16 + r_l) * K + kbase + col_l;
            __builtin_amdgcn_global_load_lds(
                (const __attribute__((address_space(1))) void*)ga,
                (__attribute__((address_space(3))) void*)(&As[buf][c * 512]),
                16, 0, 0);
        }
        int brow = n0 + w * 16 + r_l;              // B chunk w
        if (brow >= Nb) brow = Nb - 1;             // xp GEMM pad clamp
        const unsigned short* gb = B + (size_t)brow * K + kbase + col_l;
        __builtin_amdgcn_global_load_lds(
            (const __attribute__((address_space(1))) void*)gb,
            (__attribute__((address_space(3))) void*)(&Bs[buf][w * 512]),
            16, 0, 0);
    };

    int KT = Klocal / BKG;
    stage(0, 0);
    if (KT > 1) stage(1, 1);
    int u_off = (tr * 4 + (quad ^ ((tr >> 1) & 3))) * 8;   // swizzled frag addr
    for (int kt = 0; kt < KT; ++kt) {
        int cur = kt % 3;
        if (kt + 2 < KT) stage(kt + 2, (kt + 2) % 3);
        asm volatile("" ::: "memory");
        int nleft = KT - kt - 1;
        if (nleft >= 2)      __builtin_amdgcn_s_waitcnt(0x0F76);  // vmcnt(6)
        else if (nleft == 1) __builtin_amdgcn_s_waitcnt(0x0F73);  // vmcnt(3)
        else                 __builtin_amdgcn_s_waitcnt(0x0F70);  // vmcnt(0)
        __builtin_amdgcn_s_barrier();
        asm volatile("" ::: "memory");
        short8 af[2], bfr[4];
#pragma unroll
        for (int i = 0; i < 2; ++i)
            af[i] = *(const short8*)(&As[cur][(w * 2 + i) * 512 + u_off]);
#pragma unroll
        for (int i = 0; i < 4; ++i)
            bfr[i] = *(const short8*)(&Bs[cur][i * 512 + u_off]);
#pragma unroll
        for (int mi = 0; mi < 2; ++mi)
#pragma unroll
            for (int ni = 0; ni < 4; ++ni)
                acc[mi][ni] = __builtin_amdgcn_mfma_f32_16x16x32_bf16(
                    af[mi], bfr[ni], acc[mi][ni], 0, 0, 0);
        asm volatile("" ::: "memory");
        __builtin_amdgcn_s_barrier();   // protect buffer about to be re-staged
        asm volatile("" ::: "memory");
    }
    // C/D layout (m89-verified): col = lane&15, row = (lane>>4)*4 + reg
    for (int mi = 0; mi < 2; ++mi)
        for (int ni = 0; ni < 4; ++ni) {
            int col = n0 + ni * 16 + tr;
            int rowb = m0 + w * 32 + mi * 16 + quad * 4;
            for (int r = 0; r < 4; ++r) {
                size_t off = (size_t)(rowb + r) * N + col;
                float val = acc[mi][ni][r];
                if (mode == 1) {
                    atomicAdd((float*)Cv + off, val);
                } else if (mode == 2) {
                    ((unsigned short*)Cv)[off] = f2bf(val);
                } else {
                    float v2 = val + bias[col];
                    float sp = (v2 > 15.f) ? v2 : log1pf(expf(v2));
                    ((unsigned short*)Cv)[off] = f2bf(sp);
                }
            }
        }
}

// ---------------- causal depthwise conv(4) + bias + silu; bf16 in -> bf16 out ----------------
// Needed as a materialized matrix only for the x_proj GEMM's A operand.
__global__ __launch_bounds__(256) void conv_silu(
    const unsigned short* __restrict__ xz, const float* __restrict__ cw,
    const float* __restrict__ cb, unsigned short* __restrict__ xm_bf) {
    int idx = blockIdx.x * 256 + threadIdx.x;   // NTOK*DINNER
    int c = idx & (DINNER - 1);
    int tk = idx >> 11;
    int l = tk & (SEQL - 1);
    float4 wv = ((const float4*)cw)[c];
    float acc = cb[c];
    const unsigned short* base = xz + (size_t)tk * (2 * DINNER) + c;
    if (l >= 3) acc += bf2f(base[-3 * 2 * DINNER]) * wv.x;
    if (l >= 2) acc += bf2f(base[-2 * 2 * DINNER]) * wv.y;
    if (l >= 1) acc += bf2f(base[-1 * 2 * DINNER]) * wv.z;
    acc += bf2f(base[0]) * wv.w;
    float sv = acc / (1.f + expf(-acc));
    xm_bf[idx] = f2bf(sv);
}

// ---------------- extract dt-rank cols of xdbl as bf16 ----------------
__global__ __launch_bounds__(256) void extract_dt(
    const float* __restrict__ xdbl, unsigned short* __restrict__ out) {
    int i = blockIdx.x * 256 + threadIdx.x;   // NTOK*DTRANK
    int tk = i >> 6, r = i & 63;
    out[i] = f2bf(xdbl[(size_t)tk * XDS + r]);
}

// ---------------- scan phase A: local recurrence -> h_end, S (dt is bf16) ----------------
__global__ __launch_bounds__(256) void scan_a(
    const unsigned short* __restrict__ dt_bf, const unsigned short* __restrict__ xm_bf,
    const float* __restrict__ xdbl, const float* __restrict__ A_log,
    float* __restrict__ h_end, float* __restrict__ S_chunk) {
    int bid = blockIdx.x;                 // GCH*2*8 = 1024
    int g = bid >> 4, b = (bid >> 3) & 1, cbk = bid & 7;
    int c = cbk * 256 + threadIdx.x;
    __shared__ float Bsh[LC][16];
    {
        int li = threadIdx.x >> 4, s = threadIdx.x & 15;
        Bsh[li][s] = xdbl[((size_t)(b * SEQL + g * LC + li)) * XDS + 64 + s];
    }
    __syncthreads();
    float a_l2[16], h[16];
#pragma unroll
    for (int s = 0; s < 16; ++s) {
        a_l2[s] = -expf(A_log[c * 16 + s]) * 1.44269504f;
        h[s] = 0.f;
    }
    float S = 0.f;
    int rowbase = b * SEQL + g * LC;
    for (int i = 0; i < LC; ++i) {
        size_t off = (size_t)(rowbase + i) * DINNER + c;
        float dtv = bf2f(dt_bf[off]);
        S += dtv;
        float u = bf2f(xm_bf[off]);
        float bu = dtv * u;
#pragma unroll
        for (int s = 0; s < 16; ++s) {
            float dA = exp2f(dtv * a_l2[s]);
            h[s] = dA * h[s] + Bsh[i][s] * bu;
        }
    }
    int gb = g * 2 + b;
#pragma unroll
    for (int s = 0; s < 16; ++s)
        h_end[((size_t)gb * 16 + s) * DINNER + c] = h[s];
    S_chunk[(size_t)gb * DINNER + c] = S;
}

// ---------------- scan phase B: combine chunks -> h_in per chunk ----------------
__global__ __launch_bounds__(256) void scan_b(
    const float* __restrict__ A_log, const float* __restrict__ S_chunk,
    const float* __restrict__ h_end, float* __restrict__ h_in) {
    int idx = blockIdx.x * 256 + threadIdx.x;   // 2*16*2048 = 65536
    int c = idx & (DINNER - 1);
    int s = (idx >> 11) & 15;
    int b = idx >> 15;
    float a_l2 = -expf(A_log[c * 16 + s]) * 1.44269504f;
    float h = 0.f;
    for (int g = 0; g < GCH; ++g) {
        int gb = g * 2 + b;
        h_in[((size_t)gb * 16 + s) * DINNER + c] = h;
        float P = exp2f(a_l2 * S_chunk[(size_t)gb * DINNER + c]);
        h = P * h + h_end[((size_t)gb * 16 + s) * DINNER + c];
    }
}

// ---------------- scan phase C: seeded recurrence -> y (D-skip + silu(z) fused) ----------------
__global__ __launch_bounds__(256) void scan_c(
    const unsigned short* __restrict__ dt_bf, const unsigned short* __restrict__ xm_bf,
    const float* __restrict__ xdbl, const float* __restrict__ A_log,
    const float* __restrict__ D_skip, const unsigned short* __restrict__ xz,
    const float* __restrict__ h_in, unsigned short* __restrict__ y_bf) {
    int bid = blockIdx.x;                 // 1024
    int g = bid >> 4, b = (bid >> 3) & 1, cbk = bid & 7;
    int c = cbk * 256 + threadIdx.x;
    __shared__ float BCsh[LC][32];
    for (int r = 0; r < 2; ++r) {
        int e = threadIdx.x + r * 256;
        int li = e >> 5, s = e & 31;
        BCsh[li][s] = xdbl[((size_t)(b * SEQL + g * LC + li)) * XDS + 64 + s];
    }
    __syncthreads();
    int gb = g * 2 + b;
    float a_l2[16], h[16];
#pragma unroll
    for (int s = 0; s < 16; ++s) {
        a_l2[s] = -expf(A_log[c * 16 + s]) * 1.44269504f;
        h[s] = h_in[((size_t)gb * 16 + s) * DINNER + c];
    }
    float dsk = D_skip[c];
    int rowbase = b * SEQL + g * LC;
    for (int i = 0; i < LC; ++i) {
        size_t off = (size_t)(rowbase + i) * DINNER + c;
        float dtv = bf2f(dt_bf[off]);
        float u = bf2f(xm_bf[off]);
        float bu = dtv * u;
        float y = 0.f;
#pragma unroll
        for (int s = 0; s < 16; ++s) {
            float dA = exp2f(dtv * a_l2[s]);
            h[s] = dA * h[s] + BCsh[i][s] * bu;
            y += h[s] * BCsh[i][16 + s];
        }
        y += u * dsk;
        float zv = bf2f(xz[(size_t)(rowbase + i) * (2 * DINNER) + DINNER + c]);
        y *= zv / (1.f + expf(-zv));
        y_bf[off] = f2bf(y);
    }
}

extern "C" void kernel_launch(void* const* d_in, const int* in_sizes, int n_in,
                              void* d_out, int out_size, void* d_ws, size_t ws_size,
                              hipStream_t stream) {
    const float* x_in   = (const float*)d_in[0];
    const float* in_w   = (const float*)d_in[1];
    const float* conv_w = (const float*)d_in[2];
    const float* conv_b = (const float*)d_in[3];
    const float* xp_w   = (const float*)d_in[4];
    const float* dt_w   = (const float*)d_in[5];
    const float* dt_b   = (const float*)d_in[6];
    const float* A_logp = (const float*)d_in[7];
    const float* Dsk    = (const float*)d_in[8];
    const float* out_w  = (const float*)d_in[9];
    const float* ln_g   = (const float*)d_in[10];
    const float* ln_b   = (const float*)d_in[11];
    float* outp = (float*)d_out;

    char* p = (char*)d_ws;
    auto alloc = [&](size_t bytes) {
        void* r = (void*)p;
        p += (bytes + 255) & ~(size_t)255;
        return r;
    };
    float* x_res  = (float*)alloc((size_t)NTOK * DMODEL * 4);
    unsigned short* xn_bf = (unsigned short*)alloc((size_t)NTOK * DMODEL * 2);
    unsigned short* xz_bf = (unsigned short*)alloc((size_t)NTOK * 2 * DINNER * 2);
    unsigned short* xm_bf = (unsigned short*)alloc((size_t)NTOK * DINNER * 2);
    float* xdbl   = (float*)alloc((size_t)NTOK * XDS * 4);
    unsigned short* dtA_bf = (unsigned short*)alloc((size_t)NTOK * DTRANK * 2);
    unsigned short* dt_bf = (unsigned short*)alloc((size_t)NTOK * DINNER * 2);
    unsigned short* y_bf = (unsigned short*)alloc((size_t)NTOK * DINNER * 2);
    float* h_end  = (float*)alloc((size_t)GCH * 2 * 16 * DINNER * 4);
    float* h_in   = (float*)alloc((size_t)GCH * 2 * 16 * DINNER * 4);
    float* S_chunk = (float*)alloc((size_t)GCH * 2 * DINNER * 4);
    int n_inw  = 4 * 2 * DINNER * DMODEL;
    int n_xpw  = 4 * 96 * DINNER;
    int n_dtw  = 4 * DINNER * DTRANK;
    int n_outw = 4 * DMODEL * DINNER;
    unsigned short* wbf_in  = (unsigned short*)alloc((size_t)n_inw * 2);
    unsigned short* wbf_xp  = (unsigned short*)alloc((size_t)n_xpw * 2);
    unsigned short* wbf_dt  = (unsigned short*)alloc((size_t)n_dtw * 2);
    unsigned short* wbf_out = (unsigned short*)alloc((size_t)n_outw * 2);

    f32_to_bf16<<<(n_inw / 8 + 255) / 256, 256, 0, stream>>>(in_w, wbf_in, n_inw / 8);
    f32_to_bf16<<<(n_xpw / 8 + 255) / 256, 256, 0, stream>>>(xp_w, wbf_xp, n_xpw / 8);
    f32_to_bf16<<<(n_dtw / 8 + 255) / 256, 256, 0, stream>>>(dt_w, wbf_dt, n_dtw / 8);
    f32_to_bf16<<<(n_outw / 8 + 255) / 256, 256, 0, stream>>>(out_w, wbf_out, n_outw / 8);

    hipMemcpyAsync(x_res, x_in, (size_t)NTOK * DMODEL * 4,
                   hipMemcpyDeviceToDevice, stream);

    for (int L = 0; L < 4; ++L) {
        const unsigned short* w_in  = wbf_in  + (size_t)L * 2 * DINNER * DMODEL;
        const float*          w_cv  = conv_w  + (size_t)L * DINNER * 4;
        const float*          b_cv  = conv_b  + (size_t)L * DINNER;
        const unsigned short* w_xp  = wbf_xp  + (size_t)L * 96 * DINNER;
        const unsigned short* w_dt  = wbf_dt  + (size_t)L * DINNER * DTRANK;
        const float*          b_dt  = dt_b    + (size_t)L * DINNER;
        const float*          al    = A_logp  + (size_t)L * DINNER * DSTATE;
        const float*          dskl  = Dsk     + (size_t)L * DINNER;
        const unsigned short* w_out = wbf_out + (size_t)L * DMODEL * DINNER;

        ln_kernel<<<NTOK, 256, 0, stream>>>(x_res, ln_g, ln_b, xn_bf, nullptr);
        // in_proj: [2048 x 4096 x 1024] -> bf16, 1024 blocks (4/CU)
        gemm64<<<dim3(64, 16, 1), 256, 0, stream>>>(
            xn_bf, w_in, xz_bf, nullptr, NTOK, 2 * DINNER, DMODEL, 2 * DINNER, 2);
        conv_silu<<<NTOK * DINNER / 256, 256, 0, stream>>>(xz_bf, w_cv, b_cv, xm_bf);
        // x_proj: [2048 x 128(96) x 2048], split-K 8, atomic into zeroed xdbl
        zero_f32<<<NTOK * XDS / 4 / 256, 256, 0, stream>>>(xdbl, NTOK * XDS / 4);
        gemm64<<<dim3(2, 16, 8), 256, 0, stream>>>(
            xm_bf, w_xp, xdbl, nullptr, NTOK, XDS, DINNER, 96, 1);
        extract_dt<<<NTOK * DTRANK / 256, 256, 0, stream>>>(xdbl, dtA_bf);
        // dt_proj: [2048 x 2048 x 64], fused bias+softplus -> bf16, 512 blocks
        gemm64<<<dim3(32, 16, 1), 256, 0, stream>>>(
            dtA_bf, w_dt, dt_bf, b_dt, NTOK, DINNER, DTRANK, DINNER, 3);
        scan_a<<<GCH * 16, 256, 0, stream>>>(dt_bf, xm_bf, xdbl, al, h_end, S_chunk);
        scan_b<<<2 * 16 * DINNER / 256, 256, 0, stream>>>(al, S_chunk, h_end, h_in);
        scan_c<<<GCH * 16, 256, 0, stream>>>(dt_bf, xm_bf, xdbl, al, dskl, xz_bf,
                                             h_in, y_bf);
        // out_proj: [2048 x 1024 x 2048], split-K 4, atomic accumulate into x_res
        gemm64<<<dim3(16, 16, 4), 256, 0, stream>>>(
            y_bf, w_out, x_res, nullptr, NTOK, DMODEL, DINNER, DMODEL, 1);
    }
    ln_kernel<<<NTOK, 256, 0, stream>>>(x_res, ln_g, ln_b, nullptr, outp);
}

// Round 7
// 884.559 us; speedup vs baseline: 2.2180x; 1.0923x over previous
//
#include <hip/hip_runtime.h>

#define NTOK 2048      // BATCH*SEQ
#define SEQL 1024
#define DMODEL 1024
#define DINNER 2048
#define DSTATE 16
#define DTRANK 64
#define GCH 64         // scan chunks
#define LC 16          // steps per chunk
#define XDS 128        // padded xp-GEMM N (96 -> 128)

typedef __attribute__((ext_vector_type(8))) short short8;
typedef __attribute__((ext_vector_type(4))) float float4v;

__device__ __forceinline__ unsigned short f2bf(float f) {
    unsigned u = __float_as_uint(f);
    unsigned r = u + 0x7FFFu + ((u >> 16) & 1u);
    return (unsigned short)(r >> 16);
}
__device__ __forceinline__ float bf2f(unsigned short h) {
    return __uint_as_float(((unsigned)h) << 16);
}

// ---------------- f32 -> bf16 weight conversion (8 elems/thread) ----------------
__global__ __launch_bounds__(256) void f32_to_bf16(
    const float* __restrict__ in, unsigned short* __restrict__ out, int n8) {
    int i = blockIdx.x * 256 + threadIdx.x;
    if (i < n8) {
        float4 a = ((const float4*)in)[2 * i];
        float4 b = ((const float4*)in)[2 * i + 1];
        uint4 v;
        v.x = (unsigned)f2bf(a.x) | ((unsigned)f2bf(a.y) << 16);
        v.y = (unsigned)f2bf(a.z) | ((unsigned)f2bf(a.w) << 16);
        v.z = (unsigned)f2bf(b.x) | ((unsigned)f2bf(b.y) << 16);
        v.w = (unsigned)f2bf(b.z) | ((unsigned)f2bf(b.w) << 16);
        ((uint4*)out)[i] = v;
    }
}

// ---------------- LayerNorm (prologue only): f32 in -> bf16 out ----------------
__global__ __launch_bounds__(256) void ln_kernel(
    const float* __restrict__ x, const float* __restrict__ g,
    const float* __restrict__ b, unsigned short* __restrict__ out_bf) {
    int row = blockIdx.x;
    int t = threadIdx.x;
    float4 v = ((const float4*)(x + (size_t)row * DMODEL))[t];
    float s  = v.x + v.y + v.z + v.w;
    float ss = v.x*v.x + v.y*v.y + v.z*v.z + v.w*v.w;
    for (int o = 32; o; o >>= 1) { s += __shfl_xor(s, o); ss += __shfl_xor(ss, o); }
    __shared__ float red[8];
    int wv = t >> 6;
    if ((t & 63) == 0) { red[wv * 2] = s; red[wv * 2 + 1] = ss; }
    __syncthreads();
    s  = red[0] + red[2] + red[4] + red[6];
    ss = red[1] + red[3] + red[5] + red[7];
    float mu = s * (1.f / DMODEL);
    float rstd = rsqrtf(ss * (1.f / DMODEL) - mu * mu + 1e-5f);
    float4 gv = ((const float4*)g)[t];
    float4 bv = ((const float4*)b)[t];
    ((ushort4*)out_bf)[row * 256 + t] = make_ushort4(
        f2bf((v.x - mu) * rstd * gv.x + bv.x),
        f2bf((v.y - mu) * rstd * gv.y + bv.y),
        f2bf((v.z - mu) * rstd * gv.z + bv.z),
        f2bf((v.w - mu) * rstd * gv.w + bv.w));
}

// ---------------- fused: x_res += p0 + p1 ; LN(x_res) -> bf16 (or f32 final) ----------------
__global__ __launch_bounds__(256) void residual_ln(
    float* __restrict__ x_res, const float* __restrict__ p0,
    const float* __restrict__ p1, const float* __restrict__ g,
    const float* __restrict__ b, unsigned short* __restrict__ out_bf,
    float* __restrict__ out_f32) {
    int row = blockIdx.x;
    int t = threadIdx.x;
    size_t o4 = (size_t)row * 256 + t;
    float4 v  = ((const float4*)x_res)[o4];
    float4 a0 = ((const float4*)p0)[o4];
    float4 a1 = ((const float4*)p1)[o4];
    v.x += a0.x + a1.x; v.y += a0.y + a1.y;
    v.z += a0.z + a1.z; v.w += a0.w + a1.w;
    ((float4*)x_res)[o4] = v;
    float s  = v.x + v.y + v.z + v.w;
    float ss = v.x*v.x + v.y*v.y + v.z*v.z + v.w*v.w;
    for (int o = 32; o; o >>= 1) { s += __shfl_xor(s, o); ss += __shfl_xor(ss, o); }
    __shared__ float red[8];
    int wv = t >> 6;
    if ((t & 63) == 0) { red[wv * 2] = s; red[wv * 2 + 1] = ss; }
    __syncthreads();
    s  = red[0] + red[2] + red[4] + red[6];
    ss = red[1] + red[3] + red[5] + red[7];
    float mu = s * (1.f / DMODEL);
    float rstd = rsqrtf(ss * (1.f / DMODEL) - mu * mu + 1e-5f);
    float4 gv = ((const float4*)g)[t];
    float4 bv = ((const float4*)b)[t];
    float o0 = (v.x - mu) * rstd * gv.x + bv.x;
    float o1 = (v.y - mu) * rstd * gv.y + bv.y;
    float o2 = (v.z - mu) * rstd * gv.z + bv.z;
    float o3 = (v.w - mu) * rstd * gv.w + bv.w;
    if (out_f32) {
        ((float4*)out_f32)[o4] = make_float4(o0, o1, o2, o3);
    } else {
        ((ushort4*)out_bf)[o4] = make_ushort4(f2bf(o0), f2bf(o1), f2bf(o2), f2bf(o3));
    }
}

// ---------------- GEMM: C[M,N] = A[M,K](bf16) * B[N,K]^T(bf16) ----------------
// 128x64 tile, 256 threads = 4 waves on M (each wave 32x64 -> 2x4 MFMA tiles).
// Depth-3 LDS pipeline (36 KB), global_load_lds(16B), raw s_waitcnt(vmcnt)+
// s_barrier (NOT __syncthreads: drains vmcnt(0)). XOR-swizzled LDS (0 conflicts).
// Split-K via gridDim.z. Modes: 0 = f32 store into partial z (Cv + z*M*N);
// 2 = bf16 store; 3 = bf16 store of softplus(acc + bias[col]).
#define BKG 32
__global__ __launch_bounds__(256) void gemm64(
    const unsigned short* __restrict__ A, const unsigned short* __restrict__ B,
    void* __restrict__ Cv, const float* __restrict__ bias,
    int M, int N, int K, int Nb, int mode) {
    __shared__ __attribute__((aligned(16))) unsigned short As[3][128 * BKG];
    __shared__ __attribute__((aligned(16))) unsigned short Bs[3][64 * BKG];
    int m0 = blockIdx.y * 128, n0 = blockIdx.x * 64;
    int Klocal = K / gridDim.z;
    int kstart = blockIdx.z * Klocal;
    int t = threadIdx.x;
    int lane = t & 63, w = t >> 6;
    int tr = lane & 15, quad = lane >> 4;
    int r_l = lane >> 2;
    int q_l = (lane & 3) ^ ((lane >> 3) & 3);      // swizzled 16B-unit
    int col_l = q_l * 8;

    float4v acc[2][4];
    for (int mi = 0; mi < 2; ++mi)
        for (int ni = 0; ni < 4; ++ni)
            acc[mi][ni] = (float4v){0.f, 0.f, 0.f, 0.f};

    auto stage = [&](int kt, int buf) {
        int kbase = kstart + kt * BKG;
#pragma unroll
        for (int j = 0; j < 2; ++j) {
            int c = w * 2 + j;
            const unsigned short* ga = A + (size_t)(m0 + c * 16 + r_l) * K + kbase + col_l;
            __builtin_amdgcn_global_load_lds(
                (const __attribute__((address_space(1))) void*)ga,
                (__attribute__((address_space(3))) void*)(&As[buf][c * 512]),
                16, 0, 0);
        }
        int brow = n0 + w * 16 + r_l;
        if (brow >= Nb) brow = Nb - 1;
        const unsigned short* gb = B + (size_t)brow * K + kbase + col_l;
        __builtin_amdgcn_global_load_lds(
            (const __attribute__((address_space(1))) void*)gb,
            (__attribute__((address_space(3))) void*)(&Bs[buf][w * 512]),
            16, 0, 0);
    };

    int KT = Klocal / BKG;
    stage(0, 0);
    if (KT > 1) stage(1, 1);
    int u_off = (tr * 4 + (quad ^ ((tr >> 1) & 3))) * 8;
    for (int kt = 0; kt < KT; ++kt) {
        int cur = kt % 3;
        if (kt + 2 < KT) stage(kt + 2, (kt + 2) % 3);
        asm volatile("" ::: "memory");
        int nleft = KT - kt - 1;
        if (nleft >= 2)      __builtin_amdgcn_s_waitcnt(0x0F76);  // vmcnt(6)
        else if (nleft == 1) __builtin_amdgcn_s_waitcnt(0x0F73);  // vmcnt(3)
        else                 __builtin_amdgcn_s_waitcnt(0x0F70);  // vmcnt(0)
        __builtin_amdgcn_s_barrier();
        asm volatile("" ::: "memory");
        short8 af[2], bfr[4];
#pragma unroll
        for (int i = 0; i < 2; ++i)
            af[i] = *(const short8*)(&As[cur][(w * 2 + i) * 512 + u_off]);
#pragma unroll
        for (int i = 0; i < 4; ++i)
            bfr[i] = *(const short8*)(&Bs[cur][i * 512 + u_off]);
#pragma unroll
        for (int mi = 0; mi < 2; ++mi)
#pragma unroll
            for (int ni = 0; ni < 4; ++ni)
                acc[mi][ni] = __builtin_amdgcn_mfma_f32_16x16x32_bf16(
                    af[mi], bfr[ni], acc[mi][ni], 0, 0, 0);
        asm volatile("" ::: "memory");
        __builtin_amdgcn_s_barrier();
        asm volatile("" ::: "memory");
    }
    // C/D layout (m89-verified): col = lane&15, row = (lane>>4)*4 + reg
    size_t zoff = (size_t)blockIdx.z * M * N;
    for (int mi = 0; mi < 2; ++mi)
        for (int ni = 0; ni < 4; ++ni) {
            int col = n0 + ni * 16 + tr;
            int rowb = m0 + w * 32 + mi * 16 + quad * 4;
            for (int r = 0; r < 4; ++r) {
                size_t off = (size_t)(rowb + r) * N + col;
                float val = acc[mi][ni][r];
                if (mode == 0) {
                    ((float*)Cv)[zoff + off] = val;
                } else if (mode == 2) {
                    ((unsigned short*)Cv)[off] = f2bf(val);
                } else {
                    float v2 = val + bias[col];
                    float sp = (v2 > 15.f) ? v2 : log1pf(expf(v2));
                    ((unsigned short*)Cv)[off] = f2bf(sp);
                }
            }
        }
}

// ---------------- reduce 8 xp partials -> dtA(bf16) + compact BC(f32) ----------------
__global__ __launch_bounds__(256) void reduce_xp(
    const float* __restrict__ part, unsigned short* __restrict__ dtA,
    float* __restrict__ BC) {
    int i = blockIdx.x * 256 + threadIdx.x;      // NTOK*128
    int row = i >> 7, col = i & 127;
    float s = 0.f;
#pragma unroll
    for (int z = 0; z < 8; ++z)
        s += part[(size_t)z * NTOK * XDS + i];
    if (col < 64) dtA[row * 64 + col] = f2bf(s);
    else if (col < 96) BC[row * 32 + (col - 64)] = s;
}

// ---------------- causal depthwise conv(4) + bias + silu; bf16 -> bf16 ----------------
__global__ __launch_bounds__(256) void conv_silu(
    const unsigned short* __restrict__ xz, const float* __restrict__ cw,
    const float* __restrict__ cb, unsigned short* __restrict__ xm_bf) {
    int idx = blockIdx.x * 256 + threadIdx.x;   // NTOK*DINNER
    int c = idx & (DINNER - 1);
    int tk = idx >> 11;
    int l = tk & (SEQL - 1);
    float4 wv = ((const float4*)cw)[c];
    float acc = cb[c];
    const unsigned short* base = xz + (size_t)tk * (2 * DINNER) + c;
    if (l >= 3) acc += bf2f(base[-3 * 2 * DINNER]) * wv.x;
    if (l >= 2) acc += bf2f(base[-2 * 2 * DINNER]) * wv.y;
    if (l >= 1) acc += bf2f(base[-1 * 2 * DINNER]) * wv.z;
    acc += bf2f(base[0]) * wv.w;
    float sv = acc / (1.f + expf(-acc));
    xm_bf[idx] = f2bf(sv);
}

// ---------------- scan phase A: local recurrence -> h_end, S ----------------
__global__ __launch_bounds__(256) void scan_a(
    const unsigned short* __restrict__ dt_bf, const unsigned short* __restrict__ xm_bf,
    const float* __restrict__ BC, const float* __restrict__ A_log,
    float* __restrict__ h_end, float* __restrict__ S_chunk) {
    int bid = blockIdx.x;                 // GCH*2*8 = 1024
    int g = bid >> 4, b = (bid >> 3) & 1, cbk = bid & 7;
    int c = cbk * 256 + threadIdx.x;
    __shared__ float Bsh[LC][16];
    {
        int li = threadIdx.x >> 4, s = threadIdx.x & 15;
        Bsh[li][s] = BC[((size_t)(b * SEQL + g * LC + li)) * 32 + s];
    }
    __syncthreads();
    float a_l2[16], h[16];
#pragma unroll
    for (int s = 0; s < 16; ++s) {
        a_l2[s] = -expf(A_log[c * 16 + s]) * 1.44269504f;
        h[s] = 0.f;
    }
    float S = 0.f;
    int rowbase = b * SEQL + g * LC;
    for (int i = 0; i < LC; ++i) {
        size_t off = (size_t)(rowbase + i) * DINNER + c;
        float dtv = bf2f(dt_bf[off]);
        S += dtv;
        float u = bf2f(xm_bf[off]);
        float bu = dtv * u;
#pragma unroll
        for (int s = 0; s < 16; ++s) {
            float dA = exp2f(dtv * a_l2[s]);
            h[s] = dA * h[s] + Bsh[i][s] * bu;
        }
    }
    int gb = g * 2 + b;
#pragma unroll
    for (int s = 0; s < 16; ++s)
        h_end[((size_t)gb * 16 + s) * DINNER + c] = h[s];
    S_chunk[(size_t)gb * DINNER + c] = S;
}

// ---------------- scan phase B: combine chunks -> h_in per chunk ----------------
__global__ __launch_bounds__(256) void scan_b(
    const float* __restrict__ A_log, const float* __restrict__ S_chunk,
    const float* __restrict__ h_end, float* __restrict__ h_in) {
    int idx = blockIdx.x * 256 + threadIdx.x;   // 2*16*2048 = 65536
    int c = idx & (DINNER - 1);
    int s = (idx >> 11) & 15;
    int b = idx >> 15;
    float a_l2 = -expf(A_log[c * 16 + s]) * 1.44269504f;
    float h = 0.f;
    for (int g = 0; g < GCH; ++g) {
        int gb = g * 2 + b;
        h_in[((size_t)gb * 16 + s) * DINNER + c] = h;
        float P = exp2f(a_l2 * S_chunk[(size_t)gb * DINNER + c]);
        h = P * h + h_end[((size_t)gb * 16 + s) * DINNER + c];
    }
}

// ---------------- scan phase C: seeded recurrence -> y ----------------
__global__ __launch_bounds__(256) void scan_c(
    const unsigned short* __restrict__ dt_bf, const unsigned short* __restrict__ xm_bf,
    const float* __restrict__ BC, const float* __restrict__ A_log,
    const float* __restrict__ D_skip, const unsigned short* __restrict__ xz,
    const float* __restrict__ h_in, unsigned short* __restrict__ y_bf) {
    int bid = blockIdx.x;                 // 1024
    int g = bid >> 4, b = (bid >> 3) & 1, cbk = bid & 7;
    int c = cbk * 256 + threadIdx.x;
    __shared__ float BCsh[LC][32];
    for (int r = 0; r < 2; ++r) {
        int e = threadIdx.x + r * 256;
        int li = e >> 5, s = e & 31;
        BCsh[li][s] = BC[((size_t)(b * SEQL + g * LC + li)) * 32 + s];
    }
    __syncthreads();
    int gb = g * 2 + b;
    float a_l2[16], h[16];
#pragma unroll
    for (int s = 0; s < 16; ++s) {
        a_l2[s] = -expf(A_log[c * 16 + s]) * 1.44269504f;
        h[s] = h_in[((size_t)gb * 16 + s) * DINNER + c];
    }
    float dsk = D_skip[c];
    int rowbase = b * SEQL + g * LC;
    for (int i = 0; i < LC; ++i) {
        size_t off = (size_t)(rowbase + i) * DINNER + c;
        float dtv = bf2f(dt_bf[off]);
        float u = bf2f(xm_bf[off]);
        float bu = dtv * u;
        float y = 0.f;
#pragma unroll
        for (int s = 0; s < 16; ++s) {
            float dA = exp2f(dtv * a_l2[s]);
            h[s] = dA * h[s] + BCsh[i][s] * bu;
            y += h[s] * BCsh[i][16 + s];
        }
        y += u * dsk;
        float zv = bf2f(xz[(size_t)(rowbase + i) * (2 * DINNER) + DINNER + c]);
        y *= zv / (1.f + expf(-zv));
        y_bf[off] = f2bf(y);
    }
}

extern "C" void kernel_launch(void* const* d_in, const int* in_sizes, int n_in,
                              void* d_out, int out_size, void* d_ws, size_t ws_size,
                              hipStream_t stream) {
    const float* x_in   = (const float*)d_in[0];
    const float* in_w   = (const float*)d_in[1];
    const float* conv_w = (const float*)d_in[2];
    const float* conv_b = (const float*)d_in[3];
    const float* xp_w   = (const float*)d_in[4];
    const float* dt_w   = (const float*)d_in[5];
    const float* dt_b   = (const float*)d_in[6];
    const float* A_logp = (const float*)d_in[7];
    const float* Dsk    = (const float*)d_in[8];
    const float* out_w  = (const float*)d_in[9];
    const float* ln_g   = (const float*)d_in[10];
    const float* ln_b   = (const float*)d_in[11];
    float* outp = (float*)d_out;

    char* p = (char*)d_ws;
    auto alloc = [&](size_t bytes) {
        void* r = (void*)p;
        p += (bytes + 255) & ~(size_t)255;
        return r;
    };
    float* x_res  = (float*)alloc((size_t)NTOK * DMODEL * 4);
    unsigned short* xn_bf = (unsigned short*)alloc((size_t)NTOK * DMODEL * 2);
    unsigned short* xz_bf = (unsigned short*)alloc((size_t)NTOK * 2 * DINNER * 2);
    unsigned short* xm_bf = (unsigned short*)alloc((size_t)NTOK * DINNER * 2);
    float* xp_part = (float*)alloc((size_t)8 * NTOK * XDS * 4);
    float* out_part = (float*)alloc((size_t)2 * NTOK * DMODEL * 4);
    float* BC     = (float*)alloc((size_t)NTOK * 32 * 4);
    unsigned short* dtA_bf = (unsigned short*)alloc((size_t)NTOK * DTRANK * 2);
    unsigned short* dt_bf = (unsigned short*)alloc((size_t)NTOK * DINNER * 2);
    unsigned short* y_bf = (unsigned short*)alloc((size_t)NTOK * DINNER * 2);
    float* h_end  = (float*)alloc((size_t)GCH * 2 * 16 * DINNER * 4);
    float* h_in   = (float*)alloc((size_t)GCH * 2 * 16 * DINNER * 4);
    float* S_chunk = (float*)alloc((size_t)GCH * 2 * DINNER * 4);
    int n_inw  = 4 * 2 * DINNER * DMODEL;
    int n_xpw  = 4 * 96 * DINNER;
    int n_dtw  = 4 * DINNER * DTRANK;
    int n_outw = 4 * DMODEL * DINNER;
    unsigned short* wbf_in  = (unsigned short*)alloc((size_t)n_inw * 2);
    unsigned short* wbf_xp  = (unsigned short*)alloc((size_t)n_xpw * 2);
    unsigned short* wbf_dt  = (unsigned short*)alloc((size_t)n_dtw * 2);
    unsigned short* wbf_out = (unsigned short*)alloc((size_t)n_outw * 2);

    f32_to_bf16<<<(n_inw / 8 + 255) / 256, 256, 0, stream>>>(in_w, wbf_in, n_inw / 8);
    f32_to_bf16<<<(n_xpw / 8 + 255) / 256, 256, 0, stream>>>(xp_w, wbf_xp, n_xpw / 8);
    f32_to_bf16<<<(n_dtw / 8 + 255) / 256, 256, 0, stream>>>(dt_w, wbf_dt, n_dtw / 8);
    f32_to_bf16<<<(n_outw / 8 + 255) / 256, 256, 0, stream>>>(out_w, wbf_out, n_outw / 8);

    hipMemcpyAsync(x_res, x_in, (size_t)NTOK * DMODEL * 4,
                   hipMemcpyDeviceToDevice, stream);
    ln_kernel<<<NTOK, 256, 0, stream>>>(x_res, ln_g, ln_b, xn_bf);

    for (int L = 0; L < 4; ++L) {
        const unsigned short* w_in  = wbf_in  + (size_t)L * 2 * DINNER * DMODEL;
        const float*          w_cv  = conv_w  + (size_t)L * DINNER * 4;
        const float*          b_cv  = conv_b  + (size_t)L * DINNER;
        const unsigned short* w_xp  = wbf_xp  + (size_t)L * 96 * DINNER;
        const unsigned short* w_dt  = wbf_dt  + (size_t)L * DINNER * DTRANK;
        const float*          b_dt  = dt_b    + (size_t)L * DINNER;
        const float*          al    = A_logp  + (size_t)L * DINNER * DSTATE;
        const float*          dskl  = Dsk     + (size_t)L * DINNER;
        const unsigned short* w_out = wbf_out + (size_t)L * DMODEL * DINNER;

        // in_proj: [2048 x 4096 x 1024] -> bf16
        gemm64<<<dim3(64, 16, 1), 256, 0, stream>>>(
            xn_bf, w_in, xz_bf, nullptr, NTOK, 2 * DINNER, DMODEL, 2 * DINNER, 2);
        conv_silu<<<NTOK * DINNER / 256, 256, 0, stream>>>(xz_bf, w_cv, b_cv, xm_bf);
        // x_proj: [2048 x 128(96) x 2048], split-K 8 -> f32 partials
        gemm64<<<dim3(2, 16, 8), 256, 0, stream>>>(
            xm_bf, w_xp, xp_part, nullptr, NTOK, XDS, DINNER, 96, 0);
        reduce_xp<<<NTOK * XDS / 256, 256, 0, stream>>>(xp_part, dtA_bf, BC);
        // dt_proj: [2048 x 2048 x 64], fused bias+softplus -> bf16
        gemm64<<<dim3(32, 16, 1), 256, 0, stream>>>(
            dtA_bf, w_dt, dt_bf, b_dt, NTOK, DINNER, DTRANK, DINNER, 3);
        scan_a<<<GCH * 16, 256, 0, stream>>>(dt_bf, xm_bf, BC, al, h_end, S_chunk);
        scan_b<<<2 * 16 * DINNER / 256, 256, 0, stream>>>(al, S_chunk, h_end, h_in);
        scan_c<<<GCH * 16, 256, 0, stream>>>(dt_bf, xm_bf, BC, al, dskl, xz_bf,
                                             h_in, y_bf);
        // out_proj: [2048 x 1024 x 2048], split-K 2 -> f32 partials (no atomics)
        gemm64<<<dim3(16, 16, 2), 256, 0, stream>>>(
            y_bf, w_out, out_part, nullptr, NTOK, DMODEL, DINNER, DMODEL, 0);
        // fused: x_res += p0+p1; LN -> next xn (bf16) or final out (f32)
        residual_ln<<<NTOK, 256, 0, stream>>>(
            x_res, out_part, out_part + (size_t)NTOK * DMODEL, ln_g, ln_b,
            (L < 3) ? xn_bf : nullptr, (L < 3) ? nullptr : outp);
    }
}